// Round 3
// baseline (4369.716 us; speedup 1.0000x reference)
//
#include <hip/hip_runtime.h>
#include <math.h>

#define BEAM   10
#define MAXLEN 32
#define SLEN   32
#define HD     500
#define ED     500
#define G4     2000
#define PV     50000
#define NEGF   (-1e30f)

// ---------------- ws layout (float element offsets; 8-byte-aligned where needed) ----------------
#define OFF_X      0            // 32*2000 encoder input projections (+biases)
#define OFF_CBUF   64000        // 2*500  encoder c double buffer
#define OFF_GBUF   65000        // 2*2000 encoder gates double buffer
#define OFF_CTX    69000        // 32*500 encoder outputs (context)
#define OFF_DH     85000        // 10*500 decoder h
#define OFF_DC     90000        // 10*500 decoder c
#define OFF_DG     95000        // 10*2000 decoder gates
#define OFF_H2     115000       // 10*500
#define OFF_C2     120000       // 10*500
#define OFF_WCTX   125000       // 10*500
#define OFF_O      130000       // 10*500
#define OFF_SCD    135000       // double[10] beam scores (20 float slots)
#define OFF_TOK    135020       // 10 ints tokens
#define OFF_PREVK  135040       // 320 ints
#define OFF_NEXTY  135360       // 320 ints
#define OFF_PARTD  136000       // double[<=7820] sumexp partials (15640 float slots)
#define OFF_CAND   152000       // 3200 u64 candidates (6400 float slots)
#define OFF_LOG    160000       // 10*50000 logits (fp32)
#define OFF_OWT    660000       // 500*50000 transposed out_W
#define NEED_T_BYTES ((size_t)(OFF_OWT + (size_t)HD * PV) * 4)

__device__ __forceinline__ float sigf(float x) { return 1.f / (1.f + expf(-x)); }

// monotone float->uint mapping (total order preserving)
__device__ __forceinline__ unsigned fkey(float f) {
    unsigned u = __float_as_uint(f);
    return (u & 0x80000000u) ? ~u : (u | 0x80000000u);
}
__device__ __forceinline__ float unfkey(unsigned k) {
    unsigned u = (k & 0x80000000u) ? (k & 0x7fffffffu) : ~k;
    return __uint_as_float(u);
}

// ---------------- prep: X_enc[t][r] = emb[g[t]] . Wih[r] + bih[r] + bhh[r] ----------------
__global__ void k_prep(const int* __restrict__ g_seq, const float* __restrict__ enc_emb,
                       const float* __restrict__ Wih, const float* __restrict__ bih,
                       const float* __restrict__ bhh, float* __restrict__ X,
                       float* __restrict__ cbuf0) {
    if (blockIdx.x == 0) {
        for (int j = threadIdx.x; j < HD; j += 256) cbuf0[j] = 0.f;
    }
    int wv = (blockIdx.x * blockDim.x + threadIdx.x) >> 6;
    int lane = threadIdx.x & 63;
    if (wv >= SLEN * G4) return;
    int t = wv / G4, r = wv - t * G4;
    const float* emb = enc_emb + (size_t)g_seq[t] * ED;
    const float* w = Wih + (size_t)r * ED;
    float acc = 0.f;
    for (int ki = 0; ki < 8; ki++) { int k = ki * 64 + lane; if (k < ED) acc += emb[k] * w[k]; }
    for (int o = 32; o; o >>= 1) acc += __shfl_down(acc, o);
    if (lane == 0) X[t * G4 + r] = acc + bih[r] + bhh[r];
}

// ---------------- out_W transpose (p-major -> k-major) ----------------
__global__ void k_transpose(const float* __restrict__ outW, float* __restrict__ outWT) {
    __shared__ float t_lds[64][65];
    int tid = threadIdx.x;
    int pbase = blockIdx.x * 64, kbase = blockIdx.y * 64;
    for (int e = 0; e < 16; e++) {
        int idx = e * 256 + tid; int pl = idx >> 6, kl = idx & 63;
        int pp = pbase + pl, kk = kbase + kl;
        t_lds[pl][kl] = (pp < PV && kk < HD) ? outW[(size_t)pp * HD + kk] : 0.f;
    }
    __syncthreads();
    for (int e = 0; e < 16; e++) {
        int idx = e * 256 + tid; int kl = idx >> 6, pl = idx & 63;
        int pp = pbase + pl, kk = kbase + kl;
        if (pp < PV && kk < HD) outWT[(size_t)kk * PV + pp] = t_lds[pl][kl];
    }
}

// ---------------- encoder step: redundant pointwise + distributed gates ----------------
__global__ void k_enc(const float* __restrict__ Whh, const float* __restrict__ X,
                      float* __restrict__ gbuf, float* __restrict__ cbuf,
                      float* __restrict__ context, float* __restrict__ dec_h,
                      float* __restrict__ dec_c, double* __restrict__ scores,
                      int* __restrict__ tokens, int t) {
    __shared__ float h_lds[HD];
    const float* gprev = gbuf + ((t + 1) & 1) * G4;
    float*       gcur  = gbuf + (t & 1) * G4;
    const float* cprev = cbuf + ((t + 1) & 1) * HD;
    float*       ccur  = cbuf + (t & 1) * HD;
    int tid = threadIdx.x;
    if (t > 0) {
        for (int j = tid; j < HD; j += 256) {
            float gi = gprev[j], gf = gprev[HD + j], gg = gprev[2 * HD + j], go = gprev[3 * HD + j];
            float c = sigf(gf) * cprev[j] + sigf(gi) * tanhf(gg);
            float h = sigf(go) * tanhf(c);
            h_lds[j] = h;
            if (blockIdx.x == 0) {
                ccur[j] = c;
                context[(t - 1) * HD + j] = h;
                if (t == SLEN) {
                    for (int b = 0; b < BEAM; b++) { dec_h[b * HD + j] = h; dec_c[b * HD + j] = c; }
                }
            }
        }
    } else {
        for (int j = tid; j < HD; j += 256) h_lds[j] = 0.f;
    }
    if (t == SLEN && blockIdx.x == 0 && tid == 0) {
        for (int b = 0; b < BEAM; b++) scores[b] = 0.0;
        tokens[0] = 2; for (int b = 1; b < BEAM; b++) tokens[b] = 1;
    }
    __syncthreads();
    if (t < SLEN) {
        int wv = blockIdx.x * 4 + (tid >> 6), lane = tid & 63;
        for (int r = wv; r < G4; r += 1000) {
            const float* w = Whh + (size_t)r * HD;
            float acc = 0.f;
            for (int ki = 0; ki < 8; ki++) { int k = ki * 64 + lane; if (k < HD) acc += h_lds[k] * w[k]; }
            for (int o = 32; o; o >>= 1) acc += __shfl_down(acc, o);
            if (lane == 0) gcur[r] = X[t * G4 + r] + acc;
        }
    }
}

// ---------------- decoder gates: 2000 rows, 10 beams each ----------------
__global__ __launch_bounds__(1024) void k_gates(
        const float* __restrict__ dec_emb, const float* __restrict__ Wih,
        const float* __restrict__ Whh, const float* __restrict__ bih,
        const float* __restrict__ bhh, const int* __restrict__ tokens,
        const float* __restrict__ h_ws, float* __restrict__ gates) {
    __shared__ float e_lds[BEAM * ED];
    __shared__ float h_lds[BEAM * HD];
    int tid = threadIdx.x;
    for (int idx = tid; idx < BEAM * ED; idx += 1024) {
        int b = idx / ED, k = idx - b * ED;
        e_lds[idx] = dec_emb[(size_t)tokens[b] * ED + k];
        h_lds[idx] = h_ws[idx];
    }
    __syncthreads();
    int wv = tid >> 6, lane = tid & 63;
    int r = blockIdx.x * 16 + wv;
    const float* wi = Wih + (size_t)r * ED;
    const float* wh = Whh + (size_t)r * HD;
    float acc[BEAM];
#pragma unroll
    for (int b = 0; b < BEAM; b++) acc[b] = 0.f;
    for (int ki = 0; ki < 8; ki++) {
        int k = ki * 64 + lane;
        if (k < ED) {
            float w = wi[k];
#pragma unroll
            for (int b = 0; b < BEAM; b++) acc[b] += w * e_lds[b * ED + k];
        }
    }
    for (int ki = 0; ki < 8; ki++) {
        int k = ki * 64 + lane;
        if (k < HD) {
            float w = wh[k];
#pragma unroll
            for (int b = 0; b < BEAM; b++) acc[b] += w * h_lds[b * HD + k];
        }
    }
#pragma unroll
    for (int b = 0; b < BEAM; b++) {
        float v = acc[b];
        for (int o = 32; o; o >>= 1) v += __shfl_down(v, o);
        acc[b] = v;
    }
    if (lane == 0) {
        float bb = bih[r] + bhh[r];
#pragma unroll
        for (int b = 0; b < BEAM; b++) gates[b * G4 + r] = acc[b] + bb;
    }
}

// ---------------- pointwise LSTM + attention + wctx (one block per beam) ----------------
__global__ void k_attn(const float* __restrict__ gates, const float* __restrict__ c_ws,
                       const float* __restrict__ context, float* __restrict__ h2_ws,
                       float* __restrict__ c2_ws, float* __restrict__ wctx_ws) {
    __shared__ float h2_lds[HD];
    __shared__ float s_lds[SLEN];
    __shared__ float a_lds[SLEN];
    int b = blockIdx.x, tid = threadIdx.x;
    for (int j = tid; j < HD; j += 256) {
        float gi = gates[b * G4 + j], gf = gates[b * G4 + HD + j];
        float gg = gates[b * G4 + 2 * HD + j], go = gates[b * G4 + 3 * HD + j];
        float c = sigf(gf) * c_ws[b * HD + j] + sigf(gi) * tanhf(gg);
        float h2 = sigf(go) * tanhf(c);
        c2_ws[b * HD + j] = c; h2_ws[b * HD + j] = h2; h2_lds[j] = h2;
    }
    __syncthreads();
    int wv = tid >> 6, lane = tid & 63;
    for (int s = wv; s < SLEN; s += 4) {
        const float* ctx = context + s * HD;
        float acc = 0.f;
        for (int ki = 0; ki < 8; ki++) { int k = ki * 64 + lane; if (k < HD) acc += ctx[k] * h2_lds[k]; }
        for (int o = 32; o; o >>= 1) acc += __shfl_down(acc, o);
        if (lane == 0) s_lds[s] = acc;
    }
    __syncthreads();
    if (wv == 0) {
        float v = (lane < SLEN) ? s_lds[lane] : -INFINITY;
        float m = v;
        for (int o = 32; o; o >>= 1) m = fmaxf(m, __shfl_xor(m, o));
        float e = (lane < SLEN) ? expf(v - m) : 0.f;
        float sum = e;
        for (int o = 32; o; o >>= 1) sum += __shfl_xor(sum, o);
        if (lane < SLEN) a_lds[lane] = e / sum;
    }
    __syncthreads();
    for (int j = tid; j < HD; j += 256) {
        float w = 0.f;
        for (int s = 0; s < SLEN; s++) w += a_lds[s] * context[s * HD + j];
        wctx_ws[b * HD + j] = w;
    }
}

// ---------------- o = tanh([h2, wctx] @ attn_W^T) ----------------
__global__ void k_oproj(const float* __restrict__ attnW, const float* __restrict__ h2_ws,
                        const float* __restrict__ wctx_ws, float* __restrict__ o_ws) {
    __shared__ float hw[BEAM * 1000];
    int tid = threadIdx.x;
    for (int idx = tid; idx < BEAM * 1000; idx += 256) {
        int b = idx / 1000, k = idx - b * 1000;
        hw[idx] = (k < HD) ? h2_ws[b * HD + k] : wctx_ws[b * HD + k - HD];
    }
    __syncthreads();
    int wv = tid >> 6, lane = tid & 63;
    int j = blockIdx.x * 4 + wv;
    const float* w = attnW + (size_t)j * 1000;
    float acc[BEAM];
#pragma unroll
    for (int b = 0; b < BEAM; b++) acc[b] = 0.f;
    for (int ki = 0; ki < 16; ki++) {
        int k = ki * 64 + lane;
        if (k < 1000) {
            float wk = w[k];
#pragma unroll
            for (int b = 0; b < BEAM; b++) acc[b] += wk * hw[b * 1000 + k];
        }
    }
#pragma unroll
    for (int b = 0; b < BEAM; b++) {
        float v = acc[b];
        for (int o = 32; o; o >>= 1) v += __shfl_down(v, o);
        acc[b] = v;
    }
    if (lane == 0) {
#pragma unroll
        for (int b = 0; b < BEAM; b++) o_ws[b * HD + j] = tanhf(acc[b]);
    }
}

// ---------------- logits via transposed out_W: thread-per-column; fp64 sumexp ----------------
__global__ void k_logits_t(const float* __restrict__ outWT, const float* __restrict__ outB,
                           const float* __restrict__ o_ws, float* __restrict__ logits,
                           double* __restrict__ partials) {
    __shared__ __align__(16) float o_kb[HD * 12];
    __shared__ double redd[256];
    int tid = threadIdx.x;
    for (int idx = tid; idx < BEAM * HD; idx += 256) {
        int b = idx / HD, k = idx - b * HD;
        o_kb[k * 12 + b] = o_ws[idx];
    }
    __syncthreads();
    int p = blockIdx.x * 256 + tid;
    bool valid = (p < PV);
    int pc = valid ? p : (PV - 1);
    float acc[BEAM];
#pragma unroll
    for (int b = 0; b < BEAM; b++) acc[b] = 0.f;
    for (int k = 0; k < HD; k++) {
        float w = outWT[(size_t)k * PV + pc];
        const float4* o4 = (const float4*)&o_kb[k * 12];
        float4 a = o4[0], b4 = o4[1];
        float2 c2 = *(const float2*)&o_kb[k * 12 + 8];
        acc[0] += w * a.x;  acc[1] += w * a.y;  acc[2] += w * a.z;  acc[3] += w * a.w;
        acc[4] += w * b4.x; acc[5] += w * b4.y; acc[6] += w * b4.z; acc[7] += w * b4.w;
        acc[8] += w * c2.x; acc[9] += w * c2.y;
    }
    float ob = outB[pc];
    double eacc[BEAM];
#pragma unroll
    for (int b = 0; b < BEAM; b++) {
        float lg = acc[b] + ob;
        if (valid) logits[(size_t)b * PV + p] = lg;
        eacc[b] = valid ? exp((double)lg) : 0.0;
    }
#pragma unroll
    for (int b = 0; b < BEAM; b++) {
        __syncthreads();
        redd[tid] = eacc[b];
        __syncthreads();
        for (int s = 128; s; s >>= 1) { if (tid < s) redd[tid] += redd[tid + s]; __syncthreads(); }
        if (tid == 0) partials[blockIdx.x * BEAM + b] = redd[0];
    }
}

// ---------------- fallback logits (row-major out_W, wave-per-16-p); fp64 sumexp ----------------
__global__ void k_logits_f(const float* __restrict__ outW, const float* __restrict__ outB,
                           const float* __restrict__ o_ws, float* __restrict__ logits,
                           double* __restrict__ partials) {
    __shared__ float o_lds[BEAM * HD];
    __shared__ double ered[4][BEAM];
    int tid = threadIdx.x;
    for (int idx = tid; idx < BEAM * HD; idx += 256) o_lds[idx] = o_ws[idx];
    __syncthreads();
    int wv = tid >> 6, lane = tid & 63;
    int w = blockIdx.x * 4 + wv;
    double esum = 0.0;
    for (int pi = 0; pi < 16; pi++) {
        int p = w * 16 + pi;
        if (p >= PV) break;
        const float* wr = outW + (size_t)p * HD;
        float acc[BEAM];
#pragma unroll
        for (int b = 0; b < BEAM; b++) acc[b] = 0.f;
        for (int ki = 0; ki < 8; ki++) {
            int k = ki * 64 + lane;
            if (k < HD) {
                float x = wr[k];
#pragma unroll
                for (int b = 0; b < BEAM; b++) acc[b] += x * o_lds[b * HD + k];
            }
        }
#pragma unroll
        for (int b = 0; b < BEAM; b++)
            for (int o = 32; o; o >>= 1) acc[b] += __shfl_xor(acc[b], o);
        if (lane < BEAM) {
            float lg = 0.f;
#pragma unroll
            for (int b = 0; b < BEAM; b++) if (lane == b) lg = acc[b];
            lg += outB[p];
            logits[(size_t)lane * PV + p] = lg;
            esum += exp((double)lg);
        }
    }
    if (lane < BEAM) ered[wv][lane] = esum;
    __syncthreads();
    if (tid < BEAM) partials[blockIdx.x * BEAM + tid] =
        ered[0][tid] + ered[1][tid] + ered[2][tid] + ered[3][tid];
}

// ---------------- per-row block-local top-10 candidates (fp32 preselect; safe: in-row gaps >> fp32 noise) ----------------
__global__ void k_topk_row(const float* __restrict__ logits, unsigned long long* __restrict__ cands) {
    const int CH = 1563;
    int r = blockIdx.x >> 5, ci = blockIdx.x & 31;
    int base = ci * CH;
    int tid = threadIdx.x;
    unsigned long long key[7];
#pragma unroll
    for (int e = 0; e < 7; e++) {
        int p = base + e * 256 + tid;
        key[e] = 0ull;
        if (p < base + CH && p < PV) {
            float v = logits[(size_t)r * PV + p];
            key[e] = ((unsigned long long)fkey(v) << 32) | (unsigned)(~(unsigned)p);
        }
    }
    __shared__ unsigned long long m[256];
    for (int round = 0; round < BEAM; round++) {
        unsigned long long mx = 0ull;
#pragma unroll
        for (int e = 0; e < 7; e++) if (key[e] > mx) mx = key[e];
        m[tid] = mx;
        __syncthreads();
        for (int s = 128; s; s >>= 1) {
            if (tid < s && m[tid + s] > m[tid]) m[tid] = m[tid + s];
            __syncthreads();
        }
        unsigned long long win = m[0];
        __syncthreads();
#pragma unroll
        for (int e = 0; e < 7; e++) if (key[e] == win) key[e] = 0ull;
        if (tid == 0) cands[blockIdx.x * BEAM + round] = win;
    }
}

// ---------------- single-block merge, all-fp64 score path ----------------
__global__ void k_merge(const double* __restrict__ partials, int npart,
                        const unsigned long long* __restrict__ cands,
                        double* __restrict__ scores, int* __restrict__ tokens,
                        const float* __restrict__ h2_ws, const float* __restrict__ c2_ws,
                        float* __restrict__ h_ws, float* __restrict__ c_ws,
                        int* __restrict__ prevKs, int* __restrict__ nextYs, int t) {
    __shared__ double redd[256];
    __shared__ double lse_lds[BEAM];
    __shared__ double sc_lds[BEAM];
    __shared__ double mv[256];
    __shared__ unsigned mf[256];
    __shared__ int pk_lds[BEAM];
    __shared__ int ny_lds[BEAM];
    __shared__ double val_lds[BEAM];
    int tid = threadIdx.x;
    if (tid < BEAM) sc_lds[tid] = scores[tid];
    // per-row logsumexp in fp64
    for (int b = 0; b < BEAM; b++) {
        double s = 0.0;
        for (int j = tid; j < npart; j += 256) s += partials[j * BEAM + b];
        redd[tid] = s;
        __syncthreads();
        for (int st = 128; st; st >>= 1) { if (tid < st) redd[tid] += redd[tid + st]; __syncthreads(); }
        if (tid == 0) lse_lds[b] = log(redd[0]);
        __syncthreads();
    }
    // candidates: value in fp64, flat index for tie-break (smaller wins)
    double   cv[13];
    unsigned cf[13];
#pragma unroll
    for (int e = 0; e < 13; e++) {
        int c = e * 256 + tid;
        cv[e] = -1.0e308; cf[e] = 0xFFFFFFFFu;
        if (c < 3200) {
            unsigned long long k0 = cands[c];
            if (k0) {
                int r = c / 320;
                float v = unfkey((unsigned)(k0 >> 32));
                unsigned p = ~((unsigned)k0);
                double v2;
                if (t == 0) v2 = (r == 0) ? ((double)v - lse_lds[0]) : (double)NEGF;
                else        v2 = ((double)v - lse_lds[r]) + sc_lds[r];
                cv[e] = v2;
                cf[e] = (unsigned)r * PV + p;
            }
        }
    }
    for (int round = 0; round < BEAM; round++) {
        double bv = -1.0e308; unsigned bf = 0xFFFFFFFFu;
#pragma unroll
        for (int e = 0; e < 13; e++) {
            if (cv[e] > bv || (cv[e] == bv && cf[e] < bf)) { bv = cv[e]; bf = cf[e]; }
        }
        mv[tid] = bv; mf[tid] = bf;
        __syncthreads();
        for (int s = 128; s; s >>= 1) {
            if (tid < s) {
                if (mv[tid + s] > mv[tid] || (mv[tid + s] == mv[tid] && mf[tid + s] < mf[tid])) {
                    mv[tid] = mv[tid + s]; mf[tid] = mf[tid + s];
                }
            }
            __syncthreads();
        }
        double wvv = mv[0]; unsigned wff = mf[0];
        __syncthreads();
#pragma unroll
        for (int e = 0; e < 13; e++) {
            if (cf[e] == wff) { cv[e] = -1.0e308; cf[e] = 0xFFFFFFFFu; }
        }
        if (tid == 0) {
            int pk = (int)(wff / PV);
            int ny = (int)(wff - (unsigned)pk * PV);
            pk_lds[round] = pk; ny_lds[round] = ny; val_lds[round] = wvv;
        }
        __syncthreads();
    }
    if (tid < BEAM) {
        scores[tid] = val_lds[tid];
        tokens[tid] = ny_lds[tid];
        prevKs[t * BEAM + tid] = pk_lds[tid];
        nextYs[t * BEAM + tid] = ny_lds[tid];
    }
    __syncthreads();
    for (int idx = tid; idx < BEAM * HD; idx += 256) {
        int i = idx / HD, j = idx - i * HD;
        h_ws[idx] = h2_ws[pk_lds[i] * HD + j];
        c_ws[idx] = c2_ws[pk_lds[i] * HD + j];
    }
}

// ---------------- traceback ----------------
__global__ void k_traceback(const int* __restrict__ prevKs, const int* __restrict__ nextYs,
                            int* __restrict__ out) {
    int k = threadIdx.x;
    if (k >= BEAM) return;
    int cur = k;
    for (int t = MAXLEN - 1; t >= 0; t--) {
        out[k * MAXLEN + t] = nextYs[t * BEAM + cur];
        cur = prevKs[t * BEAM + cur];
    }
}

extern "C" void kernel_launch(void* const* d_in, const int* in_sizes, int n_in,
                              void* d_out, int out_size, void* d_ws, size_t ws_size,
                              hipStream_t stream) {
    const int*   g_seq  = (const int*)  d_in[0];
    const float* encEmb = (const float*)d_in[1];
    const float* encWih = (const float*)d_in[2];
    const float* encWhh = (const float*)d_in[3];
    const float* encBih = (const float*)d_in[4];
    const float* encBhh = (const float*)d_in[5];
    const float* decEmb = (const float*)d_in[6];
    const float* decWih = (const float*)d_in[7];
    const float* decWhh = (const float*)d_in[8];
    const float* decBih = (const float*)d_in[9];
    const float* decBhh = (const float*)d_in[10];
    const float* attnW  = (const float*)d_in[11];
    const float* outW   = (const float*)d_in[12];
    const float* outB   = (const float*)d_in[13];

    float* ws = (float*)d_ws;
    float*  X     = ws + OFF_X;
    float*  cbuf  = ws + OFF_CBUF;
    float*  gbuf  = ws + OFF_GBUF;
    float*  ctx   = ws + OFF_CTX;
    float*  dh    = ws + OFF_DH;
    float*  dc    = ws + OFF_DC;
    float*  dg    = ws + OFF_DG;
    float*  h2    = ws + OFF_H2;
    float*  c2    = ws + OFF_C2;
    float*  wctx  = ws + OFF_WCTX;
    float*  o     = ws + OFF_O;
    double* sc    = (double*)(ws + OFF_SCD);
    int*    tok   = (int*)(ws + OFF_TOK);
    int*    prevK = (int*)(ws + OFF_PREVK);
    int*    nextY = (int*)(ws + OFF_NEXTY);
    double* part  = (double*)(ws + OFF_PARTD);
    unsigned long long* cand = (unsigned long long*)(ws + OFF_CAND);
    float*  logits = ws + OFF_LOG;
    float*  outWT  = ws + OFF_OWT;

    bool bigws = (ws_size >= NEED_T_BYTES);

    k_prep<<<16000, 256, 0, stream>>>(g_seq, encEmb, encWih, encBih, encBhh, X, cbuf);
    if (bigws) k_transpose<<<dim3(782, 8), 256, 0, stream>>>(outW, outWT);

    for (int t = 0; t <= SLEN; t++)
        k_enc<<<250, 256, 0, stream>>>(encWhh, X, gbuf, cbuf, ctx, dh, dc, sc, tok, t);

    int npart = bigws ? 196 : 782;
    for (int t = 0; t < MAXLEN; t++) {
        k_gates<<<125, 1024, 0, stream>>>(decEmb, decWih, decWhh, decBih, decBhh, tok, dh, dg);
        k_attn<<<BEAM, 256, 0, stream>>>(dg, dc, ctx, h2, c2, wctx);
        k_oproj<<<125, 256, 0, stream>>>(attnW, h2, wctx, o);
        if (bigws) k_logits_t<<<196, 256, 0, stream>>>(outWT, outB, o, logits, part);
        else       k_logits_f<<<782, 256, 0, stream>>>(outW, outB, o, logits, part);
        k_topk_row<<<320, 256, 0, stream>>>(logits, cand);
        k_merge<<<1, 256, 0, stream>>>(part, npart, cand, sc, tok, h2, c2, dh, dc, prevK, nextY, t);
    }
    k_traceback<<<1, 64, 0, stream>>>(prevK, nextY, (int*)d_out);
}

// Round 4
// 4217.710 us; speedup vs baseline: 1.0360x; 1.0360x over previous
//
#include <hip/hip_runtime.h>
#include <math.h>

#define BEAM   10
#define MAXLEN 32
#define SLEN   32
#define HD     500
#define ED     500
#define G4     2000
#define PV     50000
#define NEGF   (-1e30f)

// ---------------- ws layout (float element offsets; 8-byte-aligned where needed) ----------------
#define OFF_X      0            // 32*2000 encoder input projections (+biases)
#define OFF_CBUF   64000        // 2*500  encoder c double buffer
#define OFF_GBUF   65000        // 2*2000 encoder gates double buffer
#define OFF_CTX    69000        // 32*500 encoder outputs (context)
#define OFF_DH     85000        // 10*500 decoder h
#define OFF_DC     90000        // 10*500 decoder c
#define OFF_DG     95000        // 10*2000 decoder gates
#define OFF_H2     115000       // 10*500
#define OFF_C2     120000       // 10*500
#define OFF_O      130000       // 10*500
#define OFF_SCD    135000       // double[10] beam scores (20 float slots)
#define OFF_TOK    135020       // 10 ints tokens
#define OFF_PREVK  135040       // 320 ints
#define OFF_NEXTY  135360       // 320 ints
#define OFF_PARTD  136000       // double[7820] sumexp partials (15640 float slots)
#define OFF_CAND   152000       // 3200 u64 candidates (6400 float slots)
#define OFF_LOG    160000       // 10*50000 logits (fp32)
#define OFF_OWT    660000       // 125*50000*4 blocked-transposed out_W (100 MB)
#define NEED_T_BYTES ((size_t)(OFF_OWT + (size_t)HD * PV) * 4)

typedef unsigned long long u64;

__device__ __forceinline__ float sigf(float x) { return 1.f / (1.f + expf(-x)); }

__device__ __forceinline__ unsigned fkey(float f) {
    unsigned u = __float_as_uint(f);
    return (u & 0x80000000u) ? ~u : (u | 0x80000000u);
}
__device__ __forceinline__ float unfkey(unsigned k) {
    unsigned u = (k & 0x80000000u) ? (k & 0x7fffffffu) : ~k;
    return __uint_as_float(u);
}

// ---------------- prep: X_enc[t][r] = emb[g[t]] . Wih[r] + bih[r] + bhh[r] ----------------
__global__ void k_prep(const int* __restrict__ g_seq, const float* __restrict__ enc_emb,
                       const float* __restrict__ Wih, const float* __restrict__ bih,
                       const float* __restrict__ bhh, float* __restrict__ X,
                       float* __restrict__ cbuf0) {
    if (blockIdx.x == 0) {
        for (int j = threadIdx.x; j < HD; j += 256) cbuf0[j] = 0.f;
    }
    int wv = (blockIdx.x * blockDim.x + threadIdx.x) >> 6;
    int lane = threadIdx.x & 63;
    if (wv >= SLEN * G4) return;
    int t = wv / G4, r = wv - t * G4;
    const float* emb = enc_emb + (size_t)g_seq[t] * ED;
    const float* w = Wih + (size_t)r * ED;
    float acc = 0.f;
    for (int ki = 0; ki < 8; ki++) { int k = ki * 64 + lane; if (k < ED) acc += emb[k] * w[k]; }
    for (int o = 32; o; o >>= 1) acc += __shfl_down(acc, o);
    if (lane == 0) X[t * G4 + r] = acc + bih[r] + bhh[r];
}

// ---------------- out_W blocked transpose: outW4[kb][p][4] = outW[p][4kb..4kb+3] ----------------
__global__ void k_transpose4(const float* __restrict__ outW, float* __restrict__ outW4) {
    __shared__ float t_lds[64][65];
    int tid = threadIdx.x;
    int pbase = blockIdx.x * 64, kbase = blockIdx.y * 64;
    for (int e = 0; e < 16; e++) {
        int idx = e * 256 + tid; int pl = idx >> 6, kl = idx & 63;
        int pp = pbase + pl, kk = kbase + kl;
        t_lds[pl][kl] = (pp < PV && kk < HD) ? outW[(size_t)pp * HD + kk] : 0.f;
    }
    __syncthreads();
    for (int e = 0; e < 4; e++) {
        int idx = e * 256 + tid;
        int pl = idx & 63, kb = idx >> 6;   // kb in [0,16)
        int pp = pbase + pl;
        int kglob = kbase + kb * 4;
        if (pp < PV && kglob < HD) {
            float4 v;
            v.x = t_lds[pl][kb * 4 + 0];
            v.y = t_lds[pl][kb * 4 + 1];
            v.z = t_lds[pl][kb * 4 + 2];
            v.w = t_lds[pl][kb * 4 + 3];
            *(float4*)(outW4 + ((size_t)(kbase / 4 + kb) * PV + pp) * 4) = v;
        }
    }
}

// ---------------- encoder step ----------------
__global__ void k_enc(const float* __restrict__ Whh, const float* __restrict__ X,
                      float* __restrict__ gbuf, float* __restrict__ cbuf,
                      float* __restrict__ context, float* __restrict__ dec_h,
                      float* __restrict__ dec_c, double* __restrict__ scores,
                      int* __restrict__ tokens, int t) {
    __shared__ float h_lds[HD];
    const float* gprev = gbuf + ((t + 1) & 1) * G4;
    float*       gcur  = gbuf + (t & 1) * G4;
    const float* cprev = cbuf + ((t + 1) & 1) * HD;
    float*       ccur  = cbuf + (t & 1) * HD;
    int tid = threadIdx.x;
    if (t > 0) {
        for (int j = tid; j < HD; j += 256) {
            float gi = gprev[j], gf = gprev[HD + j], gg = gprev[2 * HD + j], go = gprev[3 * HD + j];
            float c = sigf(gf) * cprev[j] + sigf(gi) * tanhf(gg);
            float h = sigf(go) * tanhf(c);
            h_lds[j] = h;
            if (blockIdx.x == 0) {
                ccur[j] = c;
                context[(t - 1) * HD + j] = h;
                if (t == SLEN) {
                    for (int b = 0; b < BEAM; b++) { dec_h[b * HD + j] = h; dec_c[b * HD + j] = c; }
                }
            }
        }
    } else {
        for (int j = tid; j < HD; j += 256) h_lds[j] = 0.f;
    }
    if (t == SLEN && blockIdx.x == 0 && tid == 0) {
        for (int b = 0; b < BEAM; b++) scores[b] = 0.0;
        tokens[0] = 2; for (int b = 1; b < BEAM; b++) tokens[b] = 1;
    }
    __syncthreads();
    if (t < SLEN) {
        int wv = blockIdx.x * 4 + (tid >> 6), lane = tid & 63;
        for (int r = wv; r < G4; r += 1000) {
            const float* w = Whh + (size_t)r * HD;
            float acc = 0.f;
            for (int ki = 0; ki < 8; ki++) { int k = ki * 64 + lane; if (k < HD) acc += h_lds[k] * w[k]; }
            for (int o = 32; o; o >>= 1) acc += __shfl_down(acc, o);
            if (lane == 0) gcur[r] = X[t * G4 + r] + acc;
        }
    }
}

// ---------------- decoder gates ----------------
__global__ __launch_bounds__(1024) void k_gates(
        const float* __restrict__ dec_emb, const float* __restrict__ Wih,
        const float* __restrict__ Whh, const float* __restrict__ bih,
        const float* __restrict__ bhh, const int* __restrict__ tokens,
        const float* __restrict__ h_ws, float* __restrict__ gates) {
    __shared__ float e_lds[BEAM * ED];
    __shared__ float h_lds[BEAM * HD];
    int tid = threadIdx.x;
    for (int idx = tid; idx < BEAM * ED; idx += 1024) {
        int b = idx / ED, k = idx - b * ED;
        e_lds[idx] = dec_emb[(size_t)tokens[b] * ED + k];
        h_lds[idx] = h_ws[idx];
    }
    __syncthreads();
    int wv = tid >> 6, lane = tid & 63;
    int r = blockIdx.x * 16 + wv;
    const float* wi = Wih + (size_t)r * ED;
    const float* wh = Whh + (size_t)r * HD;
    float acc[BEAM];
#pragma unroll
    for (int b = 0; b < BEAM; b++) acc[b] = 0.f;
    for (int ki = 0; ki < 8; ki++) {
        int k = ki * 64 + lane;
        if (k < ED) {
            float w = wi[k];
#pragma unroll
            for (int b = 0; b < BEAM; b++) acc[b] += w * e_lds[b * ED + k];
        }
    }
    for (int ki = 0; ki < 8; ki++) {
        int k = ki * 64 + lane;
        if (k < HD) {
            float w = wh[k];
#pragma unroll
            for (int b = 0; b < BEAM; b++) acc[b] += w * h_lds[b * HD + k];
        }
    }
#pragma unroll
    for (int b = 0; b < BEAM; b++) {
        float v = acc[b];
        for (int o = 32; o; o >>= 1) v += __shfl_down(v, o);
        acc[b] = v;
    }
    if (lane == 0) {
        float bb = bih[r] + bhh[r];
#pragma unroll
        for (int b = 0; b < BEAM; b++) gates[b * G4 + r] = acc[b] + bb;
    }
}

// ---------------- fused: pointwise LSTM + attention + wctx + oproj (125 blocks) ----------------
__global__ __launch_bounds__(256) void k_attn_oproj(
        const float* __restrict__ gates, const float* __restrict__ c_ws,
        const float* __restrict__ context, const float* __restrict__ attnW,
        float* __restrict__ h2_ws, float* __restrict__ c2_ws, float* __restrict__ o_ws) {
    __shared__ float h2_lds[BEAM * HD];
    __shared__ float wctx_lds[BEAM * HD];
    __shared__ float s_lds[BEAM * SLEN];
    __shared__ float a_lds[BEAM * SLEN];
    int tid = threadIdx.x;
    int wv = tid >> 6, lane = tid & 63;
    // Phase A: pointwise LSTM for all (b,j); block 0 persists h2/c2 for merge
    for (int idx = tid; idx < BEAM * HD; idx += 256) {
        int b = idx / HD, j = idx - b * HD;
        float gi = gates[b * G4 + j], gf = gates[b * G4 + HD + j];
        float gg = gates[b * G4 + 2 * HD + j], go = gates[b * G4 + 3 * HD + j];
        float c = sigf(gf) * c_ws[idx] + sigf(gi) * tanhf(gg);
        float h2 = sigf(go) * tanhf(c);
        h2_lds[idx] = h2;
        if (blockIdx.x == 0) { c2_ws[idx] = c; h2_ws[idx] = h2; }
    }
    __syncthreads();
    // Phase B: scores s[b][s] (same wave/lane assignment as previous passing version)
    for (int si = 0; si < 8; ++si) {
        int s = wv + 4 * si;
        float acc[BEAM];
#pragma unroll
        for (int b = 0; b < BEAM; b++) acc[b] = 0.f;
        for (int ki = 0; ki < 8; ki++) {
            int k = ki * 64 + lane;
            if (k < HD) {
                float c = context[s * HD + k];
#pragma unroll
                for (int b = 0; b < BEAM; b++) acc[b] += c * h2_lds[b * HD + k];
            }
        }
#pragma unroll
        for (int b = 0; b < BEAM; b++) {
            float v = acc[b];
            for (int o = 32; o; o >>= 1) v += __shfl_down(v, o);
            if (lane == 0) s_lds[b * SLEN + s] = v;
        }
    }
    __syncthreads();
    // Phase B2: softmax (bit-identical to previous k_attn)
    if (wv == 0) {
        for (int b = 0; b < BEAM; ++b) {
            float v = (lane < SLEN) ? s_lds[b * SLEN + lane] : -INFINITY;
            float m = v;
            for (int o = 32; o; o >>= 1) m = fmaxf(m, __shfl_xor(m, o));
            float e = (lane < SLEN) ? expf(v - m) : 0.f;
            float sum = e;
            for (int o = 32; o; o >>= 1) sum += __shfl_xor(sum, o);
            if (lane < SLEN) a_lds[b * SLEN + lane] = e / sum;
        }
    }
    __syncthreads();
    // Phase C: wctx[b][j], thread owns j and j+256, serial s (same order as before)
    {
        float w0[BEAM], w1[BEAM];
#pragma unroll
        for (int b = 0; b < BEAM; b++) { w0[b] = 0.f; w1[b] = 0.f; }
        int j0 = tid, j1 = tid + 256;
        for (int s = 0; s < SLEN; ++s) {
            float c0 = (j0 < HD) ? context[s * HD + j0] : 0.f;
            float c1 = (j1 < HD) ? context[s * HD + j1] : 0.f;
#pragma unroll
            for (int b = 0; b < BEAM; b++) {
                float a = a_lds[b * SLEN + s];
                w0[b] += a * c0; w1[b] += a * c1;
            }
        }
#pragma unroll
        for (int b = 0; b < BEAM; b++) {
            if (j0 < HD) wctx_lds[b * HD + j0] = w0[b];
            if (j1 < HD) wctx_lds[b * HD + j1] = w1[b];
        }
    }
    __syncthreads();
    // Phase D: o[b][j] = tanh(attnW[j] . [h2[b], wctx[b]]), j = blockIdx*4 + wv
    int j = blockIdx.x * 4 + wv;
    const float* w = attnW + (size_t)j * 1000;
    float acc[BEAM];
#pragma unroll
    for (int b = 0; b < BEAM; b++) acc[b] = 0.f;
    for (int ki = 0; ki < 16; ki++) {
        int k = ki * 64 + lane;
        if (k < 1000) {
            float wk = w[k];
#pragma unroll
            for (int b = 0; b < BEAM; b++) {
                float h = (k < HD) ? h2_lds[b * HD + k] : wctx_lds[b * HD + k - HD];
                acc[b] += wk * h;
            }
        }
    }
#pragma unroll
    for (int b = 0; b < BEAM; b++) {
        float v = acc[b];
        for (int o = 32; o; o >>= 1) v += __shfl_down(v, o);
        acc[b] = v;
    }
    if (lane == 0) {
#pragma unroll
        for (int b = 0; b < BEAM; b++) o_ws[b * HD + j] = tanhf(acc[b]);
    }
}

// ---------------- logits: blocked float4 layout, 4-way K split, fused fp64 sumexp ----------------
__global__ __launch_bounds__(256) void k_logits4(
        const float* __restrict__ outW4, const float* __restrict__ outB,
        const float* __restrict__ o_ws, float* __restrict__ logits,
        double* __restrict__ partials) {
    __shared__ __align__(16) float4 o4[BEAM * 125];   // o4[b*125+kb] = o[b][4kb..4kb+3]
    __shared__ float part[4][64][BEAM];
    int tid = threadIdx.x;
    for (int idx = tid; idx < BEAM * 125; idx += 256) {
        int b = idx / 125, kb = idx - b * 125;
        o4[idx] = *(const float4*)(o_ws + b * HD + kb * 4);
    }
    __syncthreads();
    int kc = tid >> 6, pl = tid & 63;
    int p = blockIdx.x * 64 + pl;
    int pc = (p < PV) ? p : (PV - 1);
    int kb0 = kc * 32, kb1 = (kc == 3) ? 125 : (kb0 + 32);
    float acc[BEAM];
#pragma unroll
    for (int b = 0; b < BEAM; b++) acc[b] = 0.f;
    const float4* wp = (const float4*)outW4;
    for (int kb = kb0; kb < kb1; ++kb) {
        float4 w = wp[(size_t)kb * PV + pc];
#pragma unroll
        for (int b = 0; b < BEAM; b++) {
            float4 o = o4[b * 125 + kb];
            acc[b] += w.x * o.x + w.y * o.y + w.z * o.z + w.w * o.w;
        }
    }
#pragma unroll
    for (int b = 0; b < BEAM; b++) part[kc][pl][b] = acc[b];
    __syncthreads();
    if (tid < 64) {
        int p2 = blockIdx.x * 64 + tid;
        bool valid = (p2 < PV);
        float ob = outB[valid ? p2 : 0];
        double es[BEAM];
#pragma unroll
        for (int b = 0; b < BEAM; b++) {
            float lg = part[0][tid][b] + part[1][tid][b] + part[2][tid][b] + part[3][tid][b] + ob;
            if (valid) logits[(size_t)b * PV + p2] = lg;
            es[b] = valid ? exp((double)lg) : 0.0;
        }
#pragma unroll
        for (int b = 0; b < BEAM; b++) {
            for (int o = 32; o; o >>= 1) es[b] += __shfl_down(es[b], o);
        }
        if (tid == 0) {
#pragma unroll
            for (int b = 0; b < BEAM; b++) partials[blockIdx.x * BEAM + b] = es[b];
        }
    }
}

// ---------------- fallback logits (row-major out_W); fp64 sumexp ----------------
__global__ void k_logits_f(const float* __restrict__ outW, const float* __restrict__ outB,
                           const float* __restrict__ o_ws, float* __restrict__ logits,
                           double* __restrict__ partials) {
    __shared__ float o_lds[BEAM * HD];
    __shared__ double ered[4][BEAM];
    int tid = threadIdx.x;
    for (int idx = tid; idx < BEAM * HD; idx += 256) o_lds[idx] = o_ws[idx];
    __syncthreads();
    int wv = tid >> 6, lane = tid & 63;
    int w = blockIdx.x * 4 + wv;
    double esum = 0.0;
    for (int pi = 0; pi < 16; pi++) {
        int p = w * 16 + pi;
        if (p >= PV) break;
        const float* wr = outW + (size_t)p * HD;
        float acc[BEAM];
#pragma unroll
        for (int b = 0; b < BEAM; b++) acc[b] = 0.f;
        for (int ki = 0; ki < 8; ki++) {
            int k = ki * 64 + lane;
            if (k < HD) {
                float x = wr[k];
#pragma unroll
                for (int b = 0; b < BEAM; b++) acc[b] += x * o_lds[b * HD + k];
            }
        }
#pragma unroll
        for (int b = 0; b < BEAM; b++)
            for (int o = 32; o; o >>= 1) acc[b] += __shfl_xor(acc[b], o);
        if (lane < BEAM) {
            float lg = 0.f;
#pragma unroll
            for (int b = 0; b < BEAM; b++) if (lane == b) lg = acc[b];
            lg += outB[p];
            logits[(size_t)lane * PV + p] = lg;
            esum += exp((double)lg);
        }
    }
    if (lane < BEAM) ered[wv][lane] = esum;
    __syncthreads();
    if (tid < BEAM) partials[blockIdx.x * BEAM + tid] =
        ered[0][tid] + ered[1][tid] + ered[2][tid] + ered[3][tid];
}

// ---------------- per-row chunk top-10 (shuffle-based) ----------------
__global__ __launch_bounds__(256) void k_topk_row(const float* __restrict__ logits,
                                                  u64* __restrict__ cands) {
    const int CH = 1563;
    int r = blockIdx.x >> 5, ci = blockIdx.x & 31;
    int base = ci * CH;
    int tid = threadIdx.x;
    int wv = tid >> 6, lane = tid & 63;
    u64 key[7];
#pragma unroll
    for (int e = 0; e < 7; e++) {
        int p = base + e * 256 + tid;
        key[e] = 0ull;
        if (p < base + CH && p < PV) {
            float v = logits[(size_t)r * PV + p];
            key[e] = ((u64)fkey(v) << 32) | (unsigned)(~(unsigned)p);
        }
    }
    __shared__ u64 wred[4];
    __shared__ u64 winlds;
    for (int round = 0; round < BEAM; round++) {
        u64 mx = 0ull;
#pragma unroll
        for (int e = 0; e < 7; e++) if (key[e] > mx) mx = key[e];
        for (int o = 32; o; o >>= 1) {
            u64 other = __shfl_down(mx, o);
            if (other > mx) mx = other;
        }
        if (lane == 0) wred[wv] = mx;
        __syncthreads();
        if (tid == 0) {
            u64 wn = wred[0];
            for (int i = 1; i < 4; i++) if (wred[i] > wn) wn = wred[i];
            winlds = wn;
            cands[blockIdx.x * BEAM + round] = wn;
        }
        __syncthreads();
        u64 win = winlds;
#pragma unroll
        for (int e = 0; e < 7; e++) if (key[e] == win) key[e] = 0ull;
    }
}

// ---------------- single-block merge, fp64 score path, shuffle reductions ----------------
__global__ __launch_bounds__(256) void k_merge(
        const double* __restrict__ partials, int npart,
        const u64* __restrict__ cands,
        double* __restrict__ scores, int* __restrict__ tokens,
        const float* __restrict__ h2_ws, const float* __restrict__ c2_ws,
        float* __restrict__ h_ws, float* __restrict__ c_ws,
        int* __restrict__ prevKs, int* __restrict__ nextYs, int t) {
    __shared__ double wredd[4];
    __shared__ double lse_lds[BEAM];
    __shared__ double sc_lds[BEAM];
    __shared__ double bwv[4];
    __shared__ unsigned bwf[4];
    __shared__ double winv_s;
    __shared__ unsigned winf_s;
    __shared__ int pk_lds[BEAM];
    __shared__ int ny_lds[BEAM];
    __shared__ double val_lds[BEAM];
    int tid = threadIdx.x;
    int wv = tid >> 6, lane = tid & 63;
    if (tid < BEAM) sc_lds[tid] = scores[tid];
    // per-row logsumexp (fp64)
    for (int b = 0; b < BEAM; b++) {
        double s = 0.0;
        for (int j = tid; j < npart; j += 256) s += partials[j * BEAM + b];
        for (int o = 32; o; o >>= 1) s += __shfl_down(s, o);
        if (lane == 0) wredd[wv] = s;
        __syncthreads();
        if (tid == 0) lse_lds[b] = log(wredd[0] + wredd[1] + wredd[2] + wredd[3]);
        __syncthreads();
    }
    // candidates (value double, flat index tie-break: smaller wins)
    double   cv[13];
    unsigned cf[13];
#pragma unroll
    for (int e = 0; e < 13; e++) {
        int c = e * 256 + tid;
        cv[e] = -1.0e308; cf[e] = 0xFFFFFFFFu;
        if (c < 3200) {
            u64 k0 = cands[c];
            if (k0) {
                int r = c / 320;
                float v = unfkey((unsigned)(k0 >> 32));
                unsigned p = ~((unsigned)k0);
                double v2;
                if (t == 0) v2 = (r == 0) ? ((double)v - lse_lds[0]) : (double)NEGF;
                else        v2 = ((double)v - lse_lds[r]) + sc_lds[r];
                cv[e] = v2;
                cf[e] = (unsigned)r * PV + p;
            }
        }
    }
    for (int round = 0; round < BEAM; round++) {
        double bv = -1.0e308; unsigned bf = 0xFFFFFFFFu;
#pragma unroll
        for (int e = 0; e < 13; e++) {
            if (cv[e] > bv || (cv[e] == bv && cf[e] < bf)) { bv = cv[e]; bf = cf[e]; }
        }
        for (int o = 32; o; o >>= 1) {
            double ov = __shfl_down(bv, o);
            unsigned of = __shfl_down(bf, o);
            if (ov > bv || (ov == bv && of < bf)) { bv = ov; bf = of; }
        }
        if (lane == 0) { bwv[wv] = bv; bwf[wv] = bf; }
        __syncthreads();
        if (tid == 0) {
            double xv = bwv[0]; unsigned xf = bwf[0];
            for (int i = 1; i < 4; i++) {
                if (bwv[i] > xv || (bwv[i] == xv && bwf[i] < xf)) { xv = bwv[i]; xf = bwf[i]; }
            }
            winv_s = xv; winf_s = xf;
            int pk = (int)(xf / PV);
            int ny = (int)(xf - (unsigned)pk * PV);
            pk_lds[round] = pk; ny_lds[round] = ny; val_lds[round] = xv;
        }
        __syncthreads();
        unsigned wff = winf_s;
#pragma unroll
        for (int e = 0; e < 13; e++) {
            if (cf[e] == wff) { cv[e] = -1.0e308; cf[e] = 0xFFFFFFFFu; }
        }
    }
    if (tid < BEAM) {
        scores[tid] = val_lds[tid];
        tokens[tid] = ny_lds[tid];
        prevKs[t * BEAM + tid] = pk_lds[tid];
        nextYs[t * BEAM + tid] = ny_lds[tid];
    }
    __syncthreads();
    for (int idx = tid; idx < BEAM * HD; idx += 256) {
        int i = idx / HD, j = idx - i * HD;
        h_ws[idx] = h2_ws[pk_lds[i] * HD + j];
        c_ws[idx] = c2_ws[pk_lds[i] * HD + j];
    }
}

// ---------------- traceback ----------------
__global__ void k_traceback(const int* __restrict__ prevKs, const int* __restrict__ nextYs,
                            int* __restrict__ out) {
    int k = threadIdx.x;
    if (k >= BEAM) return;
    int cur = k;
    for (int t = MAXLEN - 1; t >= 0; t--) {
        out[k * MAXLEN + t] = nextYs[t * BEAM + cur];
        cur = prevKs[t * BEAM + cur];
    }
}

extern "C" void kernel_launch(void* const* d_in, const int* in_sizes, int n_in,
                              void* d_out, int out_size, void* d_ws, size_t ws_size,
                              hipStream_t stream) {
    const int*   g_seq  = (const int*)  d_in[0];
    const float* encEmb = (const float*)d_in[1];
    const float* encWih = (const float*)d_in[2];
    const float* encWhh = (const float*)d_in[3];
    const float* encBih = (const float*)d_in[4];
    const float* encBhh = (const float*)d_in[5];
    const float* decEmb = (const float*)d_in[6];
    const float* decWih = (const float*)d_in[7];
    const float* decWhh = (const float*)d_in[8];
    const float* decBih = (const float*)d_in[9];
    const float* decBhh = (const float*)d_in[10];
    const float* attnW  = (const float*)d_in[11];
    const float* outW   = (const float*)d_in[12];
    const float* outB   = (const float*)d_in[13];

    float* ws = (float*)d_ws;
    float*  X     = ws + OFF_X;
    float*  cbuf  = ws + OFF_CBUF;
    float*  gbuf  = ws + OFF_GBUF;
    float*  ctx   = ws + OFF_CTX;
    float*  dh    = ws + OFF_DH;
    float*  dc    = ws + OFF_DC;
    float*  dg    = ws + OFF_DG;
    float*  h2    = ws + OFF_H2;
    float*  c2    = ws + OFF_C2;
    float*  o     = ws + OFF_O;
    double* sc    = (double*)(ws + OFF_SCD);
    int*    tok   = (int*)(ws + OFF_TOK);
    int*    prevK = (int*)(ws + OFF_PREVK);
    int*    nextY = (int*)(ws + OFF_NEXTY);
    double* part  = (double*)(ws + OFF_PARTD);
    u64*    cand  = (u64*)(ws + OFF_CAND);
    float*  logits = ws + OFF_LOG;
    float*  outW4  = ws + OFF_OWT;

    bool bigws = (ws_size >= NEED_T_BYTES);

    k_prep<<<16000, 256, 0, stream>>>(g_seq, encEmb, encWih, encBih, encBhh, X, cbuf);
    if (bigws) k_transpose4<<<dim3(782, 8), 256, 0, stream>>>(outW, outW4);

    for (int t = 0; t <= SLEN; t++)
        k_enc<<<250, 256, 0, stream>>>(encWhh, X, gbuf, cbuf, ctx, dh, dc, sc, tok, t);

    const int npart = 782;
    for (int t = 0; t < MAXLEN; t++) {
        k_gates<<<125, 1024, 0, stream>>>(decEmb, decWih, decWhh, decBih, decBhh, tok, dh, dg);
        k_attn_oproj<<<125, 256, 0, stream>>>(dg, dc, ctx, attnW, h2, c2, o);
        if (bigws) k_logits4<<<782, 256, 0, stream>>>(outW4, outB, o, logits, part);
        else       k_logits_f<<<782, 256, 0, stream>>>(outW, outB, o, logits, part);
        k_topk_row<<<320, 256, 0, stream>>>(logits, cand);
        k_merge<<<1, 256, 0, stream>>>(part, npart, cand, sc, tok, h2, c2, dh, dc, prevK, nextY, t);
    }
    k_traceback<<<1, 64, 0, stream>>>(prevK, nextY, (int*)d_out);
}

// Round 6
// 4217.218 us; speedup vs baseline: 1.0362x; 1.0001x over previous
//
#include <hip/hip_runtime.h>
#include <hip/hip_cooperative_groups.h>
#include <math.h>

namespace cg = cooperative_groups;

#define BEAM   10
#define MAXLEN 32
#define SLEN   32
#define HD     500
#define ED     500
#define G4     2000
#define PV     50000
#define NEGF   (-1e30f)

#define GRID   256          // 1 block/CU on MI355X: co-residency guaranteed (LDS 43.5KB<160KB, 1 wave/SIMD so VGPR<=512)
#define NW     1024         // GRID*4 waves

// mega topk/merge geometry (256-block schedule)
#define NCHUNK 25           // chunks per row
#define CHSZ   2000         // elements per chunk
#define CANDN  (NCHUNK * BEAM * BEAM)  // 25*10 blocks * 10 cands = 2500

// ---------------- ws layout (float element offsets) ----------------
#define OFF_X      0
#define OFF_CBUF   64000
#define OFF_GBUF   65000
#define OFF_CTX    69000
#define OFF_DH     85000
#define OFF_DC     90000
#define OFF_DG     95000
#define OFF_H2     115000
#define OFF_C2     120000
#define OFF_O      130000
#define OFF_SCD    135000
#define OFF_TOK    135020
#define OFF_PREVK  135040
#define OFF_NEXTY  135360
#define OFF_PARTD  136000
#define OFF_CAND   152000
#define OFF_LOG    160000
#define OFF_OWT    660000
#define NEED_T_BYTES ((size_t)(OFF_OWT + (size_t)HD * PV) * 4)

typedef unsigned long long u64;

__device__ __forceinline__ float sigf(float x) { return 1.f / (1.f + expf(-x)); }

__device__ __forceinline__ unsigned fkey(float f) {
    unsigned u = __float_as_uint(f);
    return (u & 0x80000000u) ? ~u : (u | 0x80000000u);
}
__device__ __forceinline__ float unfkey(unsigned k) {
    unsigned u = (k & 0x80000000u) ? (k & 0x7fffffffu) : ~k;
    return __uint_as_float(u);
}

// ---------------- prep ----------------
__global__ void k_prep(const int* __restrict__ g_seq, const float* __restrict__ enc_emb,
                       const float* __restrict__ Wih, const float* __restrict__ bih,
                       const float* __restrict__ bhh, float* __restrict__ X,
                       float* __restrict__ cbuf0) {
    if (blockIdx.x == 0) {
        for (int j = threadIdx.x; j < HD; j += 256) cbuf0[j] = 0.f;
    }
    int wv = (blockIdx.x * blockDim.x + threadIdx.x) >> 6;
    int lane = threadIdx.x & 63;
    if (wv >= SLEN * G4) return;
    int t = wv / G4, r = wv - t * G4;
    const float* emb = enc_emb + (size_t)g_seq[t] * ED;
    const float* w = Wih + (size_t)r * ED;
    float acc = 0.f;
    for (int ki = 0; ki < 8; ki++) { int k = ki * 64 + lane; if (k < ED) acc += emb[k] * w[k]; }
    for (int o = 32; o; o >>= 1) acc += __shfl_down(acc, o);
    if (lane == 0) X[t * G4 + r] = acc + bih[r] + bhh[r];
}

// ---------------- out_W blocked transpose ----------------
__global__ void k_transpose4(const float* __restrict__ outW, float* __restrict__ outW4) {
    __shared__ float t_lds[64][65];
    int tid = threadIdx.x;
    int pbase = blockIdx.x * 64, kbase = blockIdx.y * 64;
    for (int e = 0; e < 16; e++) {
        int idx = e * 256 + tid; int pl = idx >> 6, kl = idx & 63;
        int pp = pbase + pl, kk = kbase + kl;
        t_lds[pl][kl] = (pp < PV && kk < HD) ? outW[(size_t)pp * HD + kk] : 0.f;
    }
    __syncthreads();
    for (int e = 0; e < 4; e++) {
        int idx = e * 256 + tid;
        int pl = idx & 63, kb = idx >> 6;
        int pp = pbase + pl;
        int kglob = kbase + kb * 4;
        if (pp < PV && kglob < HD) {
            float4 v;
            v.x = t_lds[pl][kb * 4 + 0];
            v.y = t_lds[pl][kb * 4 + 1];
            v.z = t_lds[pl][kb * 4 + 2];
            v.w = t_lds[pl][kb * 4 + 3];
            *(float4*)(outW4 + ((size_t)(kbase / 4 + kb) * PV + pp) * 4) = v;
        }
    }
}

// ================= mega-kernel args =================
struct MegaA {
    const float* encWhh; const float* X;
    float* gbuf; float* cbuf; float* ctx;
    const float* decEmb; const float* decWih; const float* decWhh;
    const float* decBih; const float* decBhh; const float* attnW;
    const float* outW4; const float* outW; const float* outB;
    float* dh; float* dc; float* dg; float* h2w; float* c2w; float* ow;
    float* logits; double* sc; double* part;
    int* tok; int* prevK; int* nextY; u64* cand; int* outTok;
    int bigws; int npart;
};

struct TopkSm { u64 wred[4]; u64 win; };
struct MergeSm {
    double wredd[4];
    double lse[BEAM];
    double scl[BEAM];
    double bwv[4];
    unsigned bwf[4];
    unsigned winf;
    int pk[BEAM]; int ny[BEAM];
    double val[BEAM];
};

// ================= cooperative mega-kernel (GRID=256, 1 block/CU) =================
__global__ __launch_bounds__(256) void k_mega(MegaA A) {
    __shared__ __align__(16) char smem_raw[43584];
    float* smf = (float*)smem_raw;
    cg::grid_group grid = cg::this_grid();
    const int tid = threadIdx.x, bid = blockIdx.x;
    const int wv = tid >> 6, lane = tid & 63;
    const int gw = bid * 4 + wv;

    // ===== encoder: 33 steps =====
    for (int t = 0; t <= SLEN; ++t) {
        const float* gprev = A.gbuf + ((t + 1) & 1) * G4;
        float*       gcur  = A.gbuf + (t & 1) * G4;
        const float* cprev = A.cbuf + ((t + 1) & 1) * HD;
        float*       ccur  = A.cbuf + (t & 1) * HD;
        bool par = (t < SLEN) || (bid == 0);
        if (par) {
            float* h_lds = smf;
            if (t > 0) {
                for (int j = tid; j < HD; j += 256) {
                    float gi = gprev[j], gf = gprev[HD + j], gg = gprev[2 * HD + j], go = gprev[3 * HD + j];
                    float c = sigf(gf) * cprev[j] + sigf(gi) * tanhf(gg);
                    float h = sigf(go) * tanhf(c);
                    h_lds[j] = h;
                    if (bid == 0) {
                        ccur[j] = c;
                        A.ctx[(t - 1) * HD + j] = h;
                        if (t == SLEN) {
                            for (int b = 0; b < BEAM; b++) { A.dh[b * HD + j] = h; A.dc[b * HD + j] = c; }
                        }
                    }
                }
            } else {
                for (int j = tid; j < HD; j += 256) h_lds[j] = 0.f;
            }
            if (t == SLEN && bid == 0 && tid == 0) {
                for (int b = 0; b < BEAM; b++) A.sc[b] = 0.0;
                A.tok[0] = 2; for (int b = 1; b < BEAM; b++) A.tok[b] = 1;
            }
            __syncthreads();
            if (t < SLEN) {
                for (int r = gw; r < G4; r += NW) {
                    const float* w = A.encWhh + (size_t)r * HD;
                    float acc = 0.f;
                    for (int ki = 0; ki < 8; ki++) { int k = ki * 64 + lane; if (k < HD) acc += h_lds[k] * w[k]; }
                    for (int o = 32; o; o >>= 1) acc += __shfl_down(acc, o);
                    if (lane == 0) gcur[r] = A.X[t * G4 + r] + acc;
                }
            }
        }
        grid.sync();
    }

    // ===== decode: 32 steps x 5 phases =====
    for (int t = 0; t < MAXLEN; ++t) {
        // ---- phase G: gates (all blocks, 2 rows/wave) ----
        {
            float* e_lds = smf;
            float* h_lds = smf + BEAM * ED;
            for (int idx = tid; idx < BEAM * ED; idx += 256) {
                int b = idx / ED, k = idx - b * ED;
                e_lds[idx] = A.decEmb[(size_t)A.tok[b] * ED + k];
                h_lds[idx] = A.dh[idx];
            }
            __syncthreads();
            for (int r = gw; r < G4; r += NW) {
                const float* wi = A.decWih + (size_t)r * ED;
                const float* wh = A.decWhh + (size_t)r * HD;
                float acc[BEAM];
#pragma unroll
                for (int b = 0; b < BEAM; b++) acc[b] = 0.f;
                for (int ki = 0; ki < 8; ki++) {
                    int k = ki * 64 + lane;
                    if (k < ED) {
                        float w = wi[k];
#pragma unroll
                        for (int b = 0; b < BEAM; b++) acc[b] += w * e_lds[b * ED + k];
                    }
                }
                for (int ki = 0; ki < 8; ki++) {
                    int k = ki * 64 + lane;
                    if (k < HD) {
                        float w = wh[k];
#pragma unroll
                        for (int b = 0; b < BEAM; b++) acc[b] += w * h_lds[b * HD + k];
                    }
                }
#pragma unroll
                for (int b = 0; b < BEAM; b++) {
                    float v = acc[b];
                    for (int o = 32; o; o >>= 1) v += __shfl_down(v, o);
                    acc[b] = v;
                }
                if (lane == 0) {
                    float bb = A.decBih[r] + A.decBhh[r];
#pragma unroll
                    for (int b = 0; b < BEAM; b++) A.dg[b * G4 + r] = acc[b] + bb;
                }
            }
        }
        grid.sync();

        // ---- phase A: pointwise LSTM + attention + wctx + oproj (blocks 0..124) ----
        if (bid < 125) {
            float* h2_lds   = smf;
            float* wctx_lds = smf + 5000;
            float* s_lds    = smf + 10000;
            float* a_lds    = smf + 10320;
            for (int idx = tid; idx < BEAM * HD; idx += 256) {
                int b = idx / HD, j = idx - b * HD;
                float gi = A.dg[b * G4 + j], gf = A.dg[b * G4 + HD + j];
                float gg = A.dg[b * G4 + 2 * HD + j], go = A.dg[b * G4 + 3 * HD + j];
                float c = sigf(gf) * A.dc[idx] + sigf(gi) * tanhf(gg);
                float h2 = sigf(go) * tanhf(c);
                h2_lds[idx] = h2;
                if (bid == 0) { A.c2w[idx] = c; A.h2w[idx] = h2; }
            }
            __syncthreads();
            for (int si = 0; si < 8; ++si) {
                int s = wv + 4 * si;
                float acc[BEAM];
#pragma unroll
                for (int b = 0; b < BEAM; b++) acc[b] = 0.f;
                for (int ki = 0; ki < 8; ki++) {
                    int k = ki * 64 + lane;
                    if (k < HD) {
                        float c = A.ctx[s * HD + k];
#pragma unroll
                        for (int b = 0; b < BEAM; b++) acc[b] += c * h2_lds[b * HD + k];
                    }
                }
#pragma unroll
                for (int b = 0; b < BEAM; b++) {
                    float v = acc[b];
                    for (int o = 32; o; o >>= 1) v += __shfl_down(v, o);
                    if (lane == 0) s_lds[b * SLEN + s] = v;
                }
            }
            __syncthreads();
            if (wv == 0) {
                for (int b = 0; b < BEAM; ++b) {
                    float v = (lane < SLEN) ? s_lds[b * SLEN + lane] : -INFINITY;
                    float m = v;
                    for (int o = 32; o; o >>= 1) m = fmaxf(m, __shfl_xor(m, o));
                    float e = (lane < SLEN) ? expf(v - m) : 0.f;
                    float sum = e;
                    for (int o = 32; o; o >>= 1) sum += __shfl_xor(sum, o);
                    if (lane < SLEN) a_lds[b * SLEN + lane] = e / sum;
                }
            }
            __syncthreads();
            {
                float w0[BEAM], w1[BEAM];
#pragma unroll
                for (int b = 0; b < BEAM; b++) { w0[b] = 0.f; w1[b] = 0.f; }
                int j0 = tid, j1 = tid + 256;
                for (int s = 0; s < SLEN; ++s) {
                    float c0 = (j0 < HD) ? A.ctx[s * HD + j0] : 0.f;
                    float c1 = (j1 < HD) ? A.ctx[s * HD + j1] : 0.f;
#pragma unroll
                    for (int b = 0; b < BEAM; b++) {
                        float a = a_lds[b * SLEN + s];
                        w0[b] += a * c0; w1[b] += a * c1;
                    }
                }
#pragma unroll
                for (int b = 0; b < BEAM; b++) {
                    if (j0 < HD) wctx_lds[b * HD + j0] = w0[b];
                    if (j1 < HD) wctx_lds[b * HD + j1] = w1[b];
                }
            }
            __syncthreads();
            int j = gw;
            const float* w = A.attnW + (size_t)j * 1000;
            float acc[BEAM];
#pragma unroll
            for (int b = 0; b < BEAM; b++) acc[b] = 0.f;
            for (int ki = 0; ki < 16; ki++) {
                int k = ki * 64 + lane;
                if (k < 1000) {
                    float wk = w[k];
#pragma unroll
                    for (int b = 0; b < BEAM; b++) {
                        float h = (k < HD) ? h2_lds[b * HD + k] : wctx_lds[b * HD + k - HD];
                        acc[b] += wk * h;
                    }
                }
            }
#pragma unroll
            for (int b = 0; b < BEAM; b++) {
                float v = acc[b];
                for (int o = 32; o; o >>= 1) v += __shfl_down(v, o);
                acc[b] = v;
            }
            if (lane == 0) {
#pragma unroll
                for (int b = 0; b < BEAM; b++) A.ow[b * HD + j] = tanhf(acc[b]);
            }
        }
        grid.sync();

        // ---- phase L: logits + fp64 sumexp ----
        {
            float4* o4 = (float4*)smem_raw;
            for (int idx = tid; idx < BEAM * 125; idx += 256) {
                int b = idx / 125, kb = idx - b * 125;
                o4[idx] = *(const float4*)(A.ow + b * HD + kb * 4);
            }
            __syncthreads();
            if (A.bigws) {
                float* partl = (float*)(smem_raw + 20032);
                for (int pt = bid; pt < 782; pt += GRID) {
                    int kc = tid >> 6, pl = tid & 63;
                    int p = pt * 64 + pl;
                    int pc = (p < PV) ? p : (PV - 1);
                    int kb0 = kc * 32, kb1 = (kc == 3) ? 125 : (kb0 + 32);
                    float acc[BEAM];
#pragma unroll
                    for (int b = 0; b < BEAM; b++) acc[b] = 0.f;
                    const float4* wp = (const float4*)A.outW4;
                    for (int kb = kb0; kb < kb1; ++kb) {
                        float4 w = wp[(size_t)kb * PV + pc];
#pragma unroll
                        for (int b = 0; b < BEAM; b++) {
                            float4 o = o4[b * 125 + kb];
                            acc[b] += w.x * o.x + w.y * o.y + w.z * o.z + w.w * o.w;
                        }
                    }
#pragma unroll
                    for (int b = 0; b < BEAM; b++) partl[(kc * 64 + pl) * BEAM + b] = acc[b];
                    __syncthreads();
                    if (tid < 64) {
                        int p2 = pt * 64 + tid;
                        bool valid = (p2 < PV);
                        float ob = A.outB[valid ? p2 : 0];
                        double es[BEAM];
#pragma unroll
                        for (int b = 0; b < BEAM; b++) {
                            float lg = partl[(0 * 64 + tid) * BEAM + b] + partl[(1 * 64 + tid) * BEAM + b]
                                     + partl[(2 * 64 + tid) * BEAM + b] + partl[(3 * 64 + tid) * BEAM + b] + ob;
                            if (valid) A.logits[(size_t)b * PV + p2] = lg;
                            es[b] = valid ? exp((double)lg) : 0.0;
                        }
#pragma unroll
                        for (int b = 0; b < BEAM; b++) {
                            for (int o = 32; o; o >>= 1) es[b] += __shfl_down(es[b], o);
                        }
                        if (tid == 0) {
#pragma unroll
                            for (int b = 0; b < BEAM; b++) A.part[pt * BEAM + b] = es[b];
                        }
                    }
                    __syncthreads();
                }
            } else {
                float* o_lds = (float*)smem_raw;
                double* ered = (double*)(smem_raw + 20032);
                double esum = 0.0;
                for (int w = gw; w * 16 < PV; w += NW) {
                    for (int pi = 0; pi < 16; pi++) {
                        int p = w * 16 + pi;
                        if (p >= PV) break;
                        const float* wr = A.outW + (size_t)p * HD;
                        float acc[BEAM];
#pragma unroll
                        for (int b = 0; b < BEAM; b++) acc[b] = 0.f;
                        for (int ki = 0; ki < 8; ki++) {
                            int k = ki * 64 + lane;
                            if (k < HD) {
                                float x = wr[k];
#pragma unroll
                                for (int b = 0; b < BEAM; b++) acc[b] += x * o_lds[b * HD + k];
                            }
                        }
#pragma unroll
                        for (int b = 0; b < BEAM; b++)
                            for (int o = 32; o; o >>= 1) acc[b] += __shfl_xor(acc[b], o);
                        if (lane < BEAM) {
                            float lg = 0.f;
#pragma unroll
                            for (int b = 0; b < BEAM; b++) if (lane == b) lg = acc[b];
                            lg += A.outB[p];
                            A.logits[(size_t)lane * PV + p] = lg;
                            esum += exp((double)lg);
                        }
                    }
                }
                if (lane < BEAM) ered[wv * BEAM + lane] = esum;
                __syncthreads();
                if (tid < BEAM)
                    A.part[bid * BEAM + tid] = ered[0 * BEAM + tid] + ered[1 * BEAM + tid]
                                             + ered[2 * BEAM + tid] + ered[3 * BEAM + tid];
            }
        }
        grid.sync();

        // ---- phase T: per-row chunk top-10 (blocks 0..249; 25 chunks x 10 rows) ----
        if (bid < NCHUNK * BEAM) {
            TopkSm* T = (TopkSm*)smem_raw;
            int r = bid / NCHUNK, ci = bid - r * NCHUNK;
            int base = ci * CHSZ;
            u64 key[8];
#pragma unroll
            for (int e = 0; e < 8; e++) {
                int p = base + e * 256 + tid;
                key[e] = 0ull;
                if (p < base + CHSZ && p < PV) {
                    float v = A.logits[(size_t)r * PV + p];
                    key[e] = ((u64)fkey(v) << 32) | (unsigned)(~(unsigned)p);
                }
            }
            for (int round = 0; round < BEAM; round++) {
                u64 mx = 0ull;
#pragma unroll
                for (int e = 0; e < 8; e++) if (key[e] > mx) mx = key[e];
                for (int o = 32; o; o >>= 1) {
                    u64 other = __shfl_down(mx, o);
                    if (other > mx) mx = other;
                }
                if (lane == 0) T->wred[wv] = mx;
                __syncthreads();
                if (tid == 0) {
                    u64 wn = T->wred[0];
                    for (int i = 1; i < 4; i++) if (T->wred[i] > wn) wn = T->wred[i];
                    T->win = wn;
                    A.cand[bid * BEAM + round] = wn;
                }
                __syncthreads();
                u64 win = T->win;
#pragma unroll
                for (int e = 0; e < 8; e++) if (key[e] == win) key[e] = 0ull;
            }
        }
        grid.sync();

        // ---- phase M: merge (block 0) ----
        if (bid == 0) {
            MergeSm* M = (MergeSm*)smem_raw;
            if (tid < BEAM) M->scl[tid] = A.sc[tid];
            for (int b = 0; b < BEAM; b++) {
                double s = 0.0;
                for (int j = tid; j < A.npart; j += 256) s += A.part[j * BEAM + b];
                for (int o = 32; o; o >>= 1) s += __shfl_down(s, o);
                if (lane == 0) M->wredd[wv] = s;
                __syncthreads();
                if (tid == 0) M->lse[b] = log(M->wredd[0] + M->wredd[1] + M->wredd[2] + M->wredd[3]);
                __syncthreads();
            }
            double   cv[10];
            unsigned cf[10];
#pragma unroll
            for (int e = 0; e < 10; e++) {
                int c = e * 256 + tid;
                cv[e] = -1.0e308; cf[e] = 0xFFFFFFFFu;
                if (c < CANDN) {
                    u64 k0 = A.cand[c];
                    if (k0) {
                        int r = c / (NCHUNK * BEAM);
                        float v = unfkey((unsigned)(k0 >> 32));
                        unsigned p = ~((unsigned)k0);
                        double v2;
                        if (t == 0) v2 = (r == 0) ? ((double)v - M->lse[0]) : (double)NEGF;
                        else        v2 = ((double)v - M->lse[r]) + M->scl[r];
                        cv[e] = v2;
                        cf[e] = (unsigned)r * PV + p;
                    }
                }
            }
            for (int round = 0; round < BEAM; round++) {
                double bv = -1.0e308; unsigned bf = 0xFFFFFFFFu;
#pragma unroll
                for (int e = 0; e < 10; e++) {
                    if (cv[e] > bv || (cv[e] == bv && cf[e] < bf)) { bv = cv[e]; bf = cf[e]; }
                }
                for (int o = 32; o; o >>= 1) {
                    double ov = __shfl_down(bv, o);
                    unsigned of = __shfl_down(bf, o);
                    if (ov > bv || (ov == bv && of < bf)) { bv = ov; bf = of; }
                }
                if (lane == 0) { M->bwv[wv] = bv; M->bwf[wv] = bf; }
                __syncthreads();
                if (tid == 0) {
                    double xv = M->bwv[0]; unsigned xf = M->bwf[0];
                    for (int i = 1; i < 4; i++) {
                        if (M->bwv[i] > xv || (M->bwv[i] == xv && M->bwf[i] < xf)) { xv = M->bwv[i]; xf = M->bwf[i]; }
                    }
                    M->winf = xf;
                    int pk = (int)(xf / PV);
                    int ny = (int)(xf - (unsigned)pk * PV);
                    M->pk[round] = pk; M->ny[round] = ny; M->val[round] = xv;
                }
                __syncthreads();
                unsigned wff = M->winf;
#pragma unroll
                for (int e = 0; e < 10; e++) {
                    if (cf[e] == wff) { cv[e] = -1.0e308; cf[e] = 0xFFFFFFFFu; }
                }
            }
            if (tid < BEAM) {
                A.sc[tid] = M->val[tid];
                A.tok[tid] = M->ny[tid];
                A.prevK[t * BEAM + tid] = M->pk[tid];
                A.nextY[t * BEAM + tid] = M->ny[tid];
            }
            __syncthreads();
            for (int idx = tid; idx < BEAM * HD; idx += 256) {
                int i = idx / HD, j = idx - i * HD;
                A.dh[idx] = A.h2w[M->pk[i] * HD + j];
                A.dc[idx] = A.c2w[M->pk[i] * HD + j];
            }
        }
        grid.sync();
    }

    // ===== traceback (block 0) =====
    if (bid == 0 && tid < BEAM) {
        int cur = tid;
        for (int tt = MAXLEN - 1; tt >= 0; tt--) {
            A.outTok[tid * MAXLEN + tt] = A.nextY[tt * BEAM + cur];
            cur = A.prevK[tt * BEAM + cur];
        }
    }
}

// ======================================================================
// R4 fallback kernels (validated multi-launch path)
// ======================================================================
__global__ void k_enc(const float* __restrict__ Whh, const float* __restrict__ X,
                      float* __restrict__ gbuf, float* __restrict__ cbuf,
                      float* __restrict__ context, float* __restrict__ dec_h,
                      float* __restrict__ dec_c, double* __restrict__ scores,
                      int* __restrict__ tokens, int t) {
    __shared__ float h_lds[HD];
    const float* gprev = gbuf + ((t + 1) & 1) * G4;
    float*       gcur  = gbuf + (t & 1) * G4;
    const float* cprev = cbuf + ((t + 1) & 1) * HD;
    float*       ccur  = cbuf + (t & 1) * HD;
    int tid = threadIdx.x;
    if (t > 0) {
        for (int j = tid; j < HD; j += 256) {
            float gi = gprev[j], gf = gprev[HD + j], gg = gprev[2 * HD + j], go = gprev[3 * HD + j];
            float c = sigf(gf) * cprev[j] + sigf(gi) * tanhf(gg);
            float h = sigf(go) * tanhf(c);
            h_lds[j] = h;
            if (blockIdx.x == 0) {
                ccur[j] = c;
                context[(t - 1) * HD + j] = h;
                if (t == SLEN) {
                    for (int b = 0; b < BEAM; b++) { dec_h[b * HD + j] = h; dec_c[b * HD + j] = c; }
                }
            }
        }
    } else {
        for (int j = tid; j < HD; j += 256) h_lds[j] = 0.f;
    }
    if (t == SLEN && blockIdx.x == 0 && tid == 0) {
        for (int b = 0; b < BEAM; b++) scores[b] = 0.0;
        tokens[0] = 2; for (int b = 1; b < BEAM; b++) tokens[b] = 1;
    }
    __syncthreads();
    if (t < SLEN) {
        int wv = blockIdx.x * 4 + (tid >> 6), lane = tid & 63;
        for (int r = wv; r < G4; r += 1000) {
            const float* w = Whh + (size_t)r * HD;
            float acc = 0.f;
            for (int ki = 0; ki < 8; ki++) { int k = ki * 64 + lane; if (k < HD) acc += h_lds[k] * w[k]; }
            for (int o = 32; o; o >>= 1) acc += __shfl_down(acc, o);
            if (lane == 0) gcur[r] = X[t * G4 + r] + acc;
        }
    }
}

__global__ __launch_bounds__(1024) void k_gates(
        const float* __restrict__ dec_emb, const float* __restrict__ Wih,
        const float* __restrict__ Whh, const float* __restrict__ bih,
        const float* __restrict__ bhh, const int* __restrict__ tokens,
        const float* __restrict__ h_ws, float* __restrict__ gates) {
    __shared__ float e_lds[BEAM * ED];
    __shared__ float h_lds[BEAM * HD];
    int tid = threadIdx.x;
    for (int idx = tid; idx < BEAM * ED; idx += 1024) {
        int b = idx / ED, k = idx - b * ED;
        e_lds[idx] = dec_emb[(size_t)tokens[b] * ED + k];
        h_lds[idx] = h_ws[idx];
    }
    __syncthreads();
    int wv = tid >> 6, lane = tid & 63;
    int r = blockIdx.x * 16 + wv;
    const float* wi = Wih + (size_t)r * ED;
    const float* wh = Whh + (size_t)r * HD;
    float acc[BEAM];
#pragma unroll
    for (int b = 0; b < BEAM; b++) acc[b] = 0.f;
    for (int ki = 0; ki < 8; ki++) {
        int k = ki * 64 + lane;
        if (k < ED) {
            float w = wi[k];
#pragma unroll
            for (int b = 0; b < BEAM; b++) acc[b] += w * e_lds[b * ED + k];
        }
    }
    for (int ki = 0; ki < 8; ki++) {
        int k = ki * 64 + lane;
        if (k < HD) {
            float w = wh[k];
#pragma unroll
            for (int b = 0; b < BEAM; b++) acc[b] += w * h_lds[b * HD + k];
        }
    }
#pragma unroll
    for (int b = 0; b < BEAM; b++) {
        float v = acc[b];
        for (int o = 32; o; o >>= 1) v += __shfl_down(v, o);
        acc[b] = v;
    }
    if (lane == 0) {
        float bb = bih[r] + bhh[r];
#pragma unroll
        for (int b = 0; b < BEAM; b++) gates[b * G4 + r] = acc[b] + bb;
    }
}

__global__ __launch_bounds__(256) void k_attn_oproj(
        const float* __restrict__ gates, const float* __restrict__ c_ws,
        const float* __restrict__ context, const float* __restrict__ attnW,
        float* __restrict__ h2_ws, float* __restrict__ c2_ws, float* __restrict__ o_ws) {
    __shared__ float h2_lds[BEAM * HD];
    __shared__ float wctx_lds[BEAM * HD];
    __shared__ float s_lds[BEAM * SLEN];
    __shared__ float a_lds[BEAM * SLEN];
    int tid = threadIdx.x;
    int wv = tid >> 6, lane = tid & 63;
    for (int idx = tid; idx < BEAM * HD; idx += 256) {
        int b = idx / HD, j = idx - b * HD;
        float gi = gates[b * G4 + j], gf = gates[b * G4 + HD + j];
        float gg = gates[b * G4 + 2 * HD + j], go = gates[b * G4 + 3 * HD + j];
        float c = sigf(gf) * c_ws[idx] + sigf(gi) * tanhf(gg);
        float h2 = sigf(go) * tanhf(c);
        h2_lds[idx] = h2;
        if (blockIdx.x == 0) { c2_ws[idx] = c; h2_ws[idx] = h2; }
    }
    __syncthreads();
    for (int si = 0; si < 8; ++si) {
        int s = wv + 4 * si;
        float acc[BEAM];
#pragma unroll
        for (int b = 0; b < BEAM; b++) acc[b] = 0.f;
        for (int ki = 0; ki < 8; ki++) {
            int k = ki * 64 + lane;
            if (k < HD) {
                float c = context[s * HD + k];
#pragma unroll
                for (int b = 0; b < BEAM; b++) acc[b] += c * h2_lds[b * HD + k];
            }
        }
#pragma unroll
        for (int b = 0; b < BEAM; b++) {
            float v = acc[b];
            for (int o = 32; o; o >>= 1) v += __shfl_down(v, o);
            if (lane == 0) s_lds[b * SLEN + s] = v;
        }
    }
    __syncthreads();
    if (wv == 0) {
        for (int b = 0; b < BEAM; ++b) {
            float v = (lane < SLEN) ? s_lds[b * SLEN + lane] : -INFINITY;
            float m = v;
            for (int o = 32; o; o >>= 1) m = fmaxf(m, __shfl_xor(m, o));
            float e = (lane < SLEN) ? expf(v - m) : 0.f;
            float sum = e;
            for (int o = 32; o; o >>= 1) sum += __shfl_xor(sum, o);
            if (lane < SLEN) a_lds[b * SLEN + lane] = e / sum;
        }
    }
    __syncthreads();
    {
        float w0[BEAM], w1[BEAM];
#pragma unroll
        for (int b = 0; b < BEAM; b++) { w0[b] = 0.f; w1[b] = 0.f; }
        int j0 = tid, j1 = tid + 256;
        for (int s = 0; s < SLEN; ++s) {
            float c0 = (j0 < HD) ? context[s * HD + j0] : 0.f;
            float c1 = (j1 < HD) ? context[s * HD + j1] : 0.f;
#pragma unroll
            for (int b = 0; b < BEAM; b++) {
                float a = a_lds[b * SLEN + s];
                w0[b] += a * c0; w1[b] += a * c1;
            }
        }
#pragma unroll
        for (int b = 0; b < BEAM; b++) {
            if (j0 < HD) wctx_lds[b * HD + j0] = w0[b];
            if (j1 < HD) wctx_lds[b * HD + j1] = w1[b];
        }
    }
    __syncthreads();
    int j = blockIdx.x * 4 + wv;
    const float* w = attnW + (size_t)j * 1000;
    float acc[BEAM];
#pragma unroll
    for (int b = 0; b < BEAM; b++) acc[b] = 0.f;
    for (int ki = 0; ki < 16; ki++) {
        int k = ki * 64 + lane;
        if (k < 1000) {
            float wk = w[k];
#pragma unroll
            for (int b = 0; b < BEAM; b++) {
                float h = (k < HD) ? h2_lds[b * HD + k] : wctx_lds[b * HD + k - HD];
                acc[b] += wk * h;
            }
        }
    }
#pragma unroll
    for (int b = 0; b < BEAM; b++) {
        float v = acc[b];
        for (int o = 32; o; o >>= 1) v += __shfl_down(v, o);
        acc[b] = v;
    }
    if (lane == 0) {
#pragma unroll
        for (int b = 0; b < BEAM; b++) o_ws[b * HD + j] = tanhf(acc[b]);
    }
}

__global__ __launch_bounds__(256) void k_logits4(
        const float* __restrict__ outW4, const float* __restrict__ outB,
        const float* __restrict__ o_ws, float* __restrict__ logits,
        double* __restrict__ partials) {
    __shared__ __align__(16) float4 o4[BEAM * 125];
    __shared__ float part[4][64][BEAM];
    int tid = threadIdx.x;
    for (int idx = tid; idx < BEAM * 125; idx += 256) {
        int b = idx / 125, kb = idx - b * 125;
        o4[idx] = *(const float4*)(o_ws + b * HD + kb * 4);
    }
    __syncthreads();
    int kc = tid >> 6, pl = tid & 63;
    int p = blockIdx.x * 64 + pl;
    int pc = (p < PV) ? p : (PV - 1);
    int kb0 = kc * 32, kb1 = (kc == 3) ? 125 : (kb0 + 32);
    float acc[BEAM];
#pragma unroll
    for (int b = 0; b < BEAM; b++) acc[b] = 0.f;
    const float4* wp = (const float4*)outW4;
    for (int kb = kb0; kb < kb1; ++kb) {
        float4 w = wp[(size_t)kb * PV + pc];
#pragma unroll
        for (int b = 0; b < BEAM; b++) {
            float4 o = o4[b * 125 + kb];
            acc[b] += w.x * o.x + w.y * o.y + w.z * o.z + w.w * o.w;
        }
    }
#pragma unroll
    for (int b = 0; b < BEAM; b++) part[kc][pl][b] = acc[b];
    __syncthreads();
    if (tid < 64) {
        int p2 = blockIdx.x * 64 + tid;
        bool valid = (p2 < PV);
        float ob = outB[valid ? p2 : 0];
        double es[BEAM];
#pragma unroll
        for (int b = 0; b < BEAM; b++) {
            float lg = part[0][tid][b] + part[1][tid][b] + part[2][tid][b] + part[3][tid][b] + ob;
            if (valid) logits[(size_t)b * PV + p2] = lg;
            es[b] = valid ? exp((double)lg) : 0.0;
        }
#pragma unroll
        for (int b = 0; b < BEAM; b++) {
            for (int o = 32; o; o >>= 1) es[b] += __shfl_down(es[b], o);
        }
        if (tid == 0) {
#pragma unroll
            for (int b = 0; b < BEAM; b++) partials[blockIdx.x * BEAM + b] = es[b];
        }
    }
}

__global__ void k_logits_f(const float* __restrict__ outW, const float* __restrict__ outB,
                           const float* __restrict__ o_ws, float* __restrict__ logits,
                           double* __restrict__ partials) {
    __shared__ float o_lds[BEAM * HD];
    __shared__ double ered[4][BEAM];
    int tid = threadIdx.x;
    for (int idx = tid; idx < BEAM * HD; idx += 256) o_lds[idx] = o_ws[idx];
    __syncthreads();
    int wv = tid >> 6, lane = tid & 63;
    int w = blockIdx.x * 4 + wv;
    double esum = 0.0;
    for (int pi = 0; pi < 16; pi++) {
        int p = w * 16 + pi;
        if (p >= PV) break;
        const float* wr = outW + (size_t)p * HD;
        float acc[BEAM];
#pragma unroll
        for (int b = 0; b < BEAM; b++) acc[b] = 0.f;
        for (int ki = 0; ki < 8; ki++) {
            int k = ki * 64 + lane;
            if (k < HD) {
                float x = wr[k];
#pragma unroll
                for (int b = 0; b < BEAM; b++) acc[b] += x * o_lds[b * HD + k];
            }
        }
#pragma unroll
        for (int b = 0; b < BEAM; b++)
            for (int o = 32; o; o >>= 1) acc[b] += __shfl_xor(acc[b], o);
        if (lane < BEAM) {
            float lg = 0.f;
#pragma unroll
            for (int b = 0; b < BEAM; b++) if (lane == b) lg = acc[b];
            lg += outB[p];
            logits[(size_t)lane * PV + p] = lg;
            esum += exp((double)lg);
        }
    }
    if (lane < BEAM) ered[wv][lane] = esum;
    __syncthreads();
    if (tid < BEAM) partials[blockIdx.x * BEAM + tid] =
        ered[0][tid] + ered[1][tid] + ered[2][tid] + ered[3][tid];
}

__global__ __launch_bounds__(256) void k_topk_row(const float* __restrict__ logits,
                                                  u64* __restrict__ cands) {
    const int CH = 1563;
    int r = blockIdx.x >> 5, ci = blockIdx.x & 31;
    int base = ci * CH;
    int tid = threadIdx.x;
    int wv = tid >> 6, lane = tid & 63;
    u64 key[7];
#pragma unroll
    for (int e = 0; e < 7; e++) {
        int p = base + e * 256 + tid;
        key[e] = 0ull;
        if (p < base + CH && p < PV) {
            float v = logits[(size_t)r * PV + p];
            key[e] = ((u64)fkey(v) << 32) | (unsigned)(~(unsigned)p);
        }
    }
    __shared__ u64 wred[4];
    __shared__ u64 winlds;
    for (int round = 0; round < BEAM; round++) {
        u64 mx = 0ull;
#pragma unroll
        for (int e = 0; e < 7; e++) if (key[e] > mx) mx = key[e];
        for (int o = 32; o; o >>= 1) {
            u64 other = __shfl_down(mx, o);
            if (other > mx) mx = other;
        }
        if (lane == 0) wred[wv] = mx;
        __syncthreads();
        if (tid == 0) {
            u64 wn = wred[0];
            for (int i = 1; i < 4; i++) if (wred[i] > wn) wn = wred[i];
            winlds = wn;
            cands[blockIdx.x * BEAM + round] = wn;
        }
        __syncthreads();
        u64 win = winlds;
#pragma unroll
        for (int e = 0; e < 7; e++) if (key[e] == win) key[e] = 0ull;
    }
}

__global__ __launch_bounds__(256) void k_merge(
        const double* __restrict__ partials, int npart,
        const u64* __restrict__ cands,
        double* __restrict__ scores, int* __restrict__ tokens,
        const float* __restrict__ h2_ws, const float* __restrict__ c2_ws,
        float* __restrict__ h_ws, float* __restrict__ c_ws,
        int* __restrict__ prevKs, int* __restrict__ nextYs, int t) {
    __shared__ double wredd[4];
    __shared__ double lse_lds[BEAM];
    __shared__ double sc_lds[BEAM];
    __shared__ double bwv[4];
    __shared__ unsigned bwf[4];
    __shared__ unsigned winf_s;
    __shared__ int pk_lds[BEAM];
    __shared__ int ny_lds[BEAM];
    __shared__ double val_lds[BEAM];
    int tid = threadIdx.x;
    int wv = tid >> 6, lane = tid & 63;
    if (tid < BEAM) sc_lds[tid] = scores[tid];
    for (int b = 0; b < BEAM; b++) {
        double s = 0.0;
        for (int j = tid; j < npart; j += 256) s += partials[j * BEAM + b];
        for (int o = 32; o; o >>= 1) s += __shfl_down(s, o);
        if (lane == 0) wredd[wv] = s;
        __syncthreads();
        if (tid == 0) lse_lds[b] = log(wredd[0] + wredd[1] + wredd[2] + wredd[3]);
        __syncthreads();
    }
    double   cv[13];
    unsigned cf[13];
#pragma unroll
    for (int e = 0; e < 13; e++) {
        int c = e * 256 + tid;
        cv[e] = -1.0e308; cf[e] = 0xFFFFFFFFu;
        if (c < 3200) {
            u64 k0 = cands[c];
            if (k0) {
                int r = c / 320;
                float v = unfkey((unsigned)(k0 >> 32));
                unsigned p = ~((unsigned)k0);
                double v2;
                if (t == 0) v2 = (r == 0) ? ((double)v - lse_lds[0]) : (double)NEGF;
                else        v2 = ((double)v - lse_lds[r]) + sc_lds[r];
                cv[e] = v2;
                cf[e] = (unsigned)r * PV + p;
            }
        }
    }
    for (int round = 0; round < BEAM; round++) {
        double bv = -1.0e308; unsigned bf = 0xFFFFFFFFu;
#pragma unroll
        for (int e = 0; e < 13; e++) {
            if (cv[e] > bv || (cv[e] == bv && cf[e] < bf)) { bv = cv[e]; bf = cf[e]; }
        }
        for (int o = 32; o; o >>= 1) {
            double ov = __shfl_down(bv, o);
            unsigned of = __shfl_down(bf, o);
            if (ov > bv || (ov == bv && of < bf)) { bv = ov; bf = of; }
        }
        if (lane == 0) { bwv[wv] = bv; bwf[wv] = bf; }
        __syncthreads();
        if (tid == 0) {
            double xv = bwv[0]; unsigned xf = bwf[0];
            for (int i = 1; i < 4; i++) {
                if (bwv[i] > xv || (bwv[i] == xv && bwf[i] < xf)) { xv = bwv[i]; xf = bwf[i]; }
            }
            winf_s = xf;
            int pk = (int)(xf / PV);
            int ny = (int)(xf - (unsigned)pk * PV);
            pk_lds[round] = pk; ny_lds[round] = ny; val_lds[round] = xv;
        }
        __syncthreads();
        unsigned wff = winf_s;
#pragma unroll
        for (int e = 0; e < 13; e++) {
            if (cf[e] == wff) { cv[e] = -1.0e308; cf[e] = 0xFFFFFFFFu; }
        }
    }
    if (tid < BEAM) {
        scores[tid] = val_lds[tid];
        tokens[tid] = ny_lds[tid];
        prevKs[t * BEAM + tid] = pk_lds[tid];
        nextYs[t * BEAM + tid] = ny_lds[tid];
    }
    __syncthreads();
    for (int idx = tid; idx < BEAM * HD; idx += 256) {
        int i = idx / HD, j = idx - i * HD;
        h_ws[idx] = h2_ws[pk_lds[i] * HD + j];
        c_ws[idx] = c2_ws[pk_lds[i] * HD + j];
    }
}

__global__ void k_traceback(const int* __restrict__ prevKs, const int* __restrict__ nextYs,
                            int* __restrict__ out) {
    int k = threadIdx.x;
    if (k >= BEAM) return;
    int cur = k;
    for (int t = MAXLEN - 1; t >= 0; t--) {
        out[k * MAXLEN + t] = nextYs[t * BEAM + cur];
        cur = prevKs[t * BEAM + cur];
    }
}

extern "C" void kernel_launch(void* const* d_in, const int* in_sizes, int n_in,
                              void* d_out, int out_size, void* d_ws, size_t ws_size,
                              hipStream_t stream) {
    const int*   g_seq  = (const int*)  d_in[0];
    const float* encEmb = (const float*)d_in[1];
    const float* encWih = (const float*)d_in[2];
    const float* encWhh = (const float*)d_in[3];
    const float* encBih = (const float*)d_in[4];
    const float* encBhh = (const float*)d_in[5];
    const float* decEmb = (const float*)d_in[6];
    const float* decWih = (const float*)d_in[7];
    const float* decWhh = (const float*)d_in[8];
    const float* decBih = (const float*)d_in[9];
    const float* decBhh = (const float*)d_in[10];
    const float* attnW  = (const float*)d_in[11];
    const float* outW   = (const float*)d_in[12];
    const float* outB   = (const float*)d_in[13];

    float* ws = (float*)d_ws;
    float*  X     = ws + OFF_X;
    float*  cbuf  = ws + OFF_CBUF;
    float*  gbuf  = ws + OFF_GBUF;
    float*  ctx   = ws + OFF_CTX;
    float*  dh    = ws + OFF_DH;
    float*  dc    = ws + OFF_DC;
    float*  dg    = ws + OFF_DG;
    float*  h2    = ws + OFF_H2;
    float*  c2    = ws + OFF_C2;
    float*  o     = ws + OFF_O;
    double* sc    = (double*)(ws + OFF_SCD);
    int*    tok   = (int*)(ws + OFF_TOK);
    int*    prevK = (int*)(ws + OFF_PREVK);
    int*    nextY = (int*)(ws + OFF_NEXTY);
    double* part  = (double*)(ws + OFF_PARTD);
    u64*    cand  = (u64*)(ws + OFF_CAND);
    float*  logits = ws + OFF_LOG;
    float*  outW4  = ws + OFF_OWT;

    bool bigws = (ws_size >= NEED_T_BYTES);

    k_prep<<<16000, 256, 0, stream>>>(g_seq, encEmb, encWih, encBih, encBhh, X, cbuf);
    if (bigws) k_transpose4<<<dim3(782, 8), 256, 0, stream>>>(outW, outW4);

    // co-residency guard: GRID=256 needs 1 block/CU on >=256 CUs
    bool coop_ok = false;
    {
        int dev = 0;
        if (hipGetDevice(&dev) == hipSuccess) {
            hipDeviceProp_t prop;
            if (hipGetDeviceProperties(&prop, dev) == hipSuccess && prop.cooperativeLaunch) {
                int occ = 0;
                if (hipOccupancyMaxActiveBlocksPerMultiprocessor(&occ, (const void*)k_mega, 256, 0)
                        == hipSuccess) {
                    if ((long long)occ * prop.multiProcessorCount >= GRID) coop_ok = true;
                }
            }
        }
    }

    hipError_t err = hipErrorUnknown;
    if (coop_ok) {
        MegaA a;
        a.encWhh = encWhh; a.X = X;
        a.gbuf = gbuf; a.cbuf = cbuf; a.ctx = ctx;
        a.decEmb = decEmb; a.decWih = decWih; a.decWhh = decWhh;
        a.decBih = decBih; a.decBhh = decBhh; a.attnW = attnW;
        a.outW4 = outW4; a.outW = outW; a.outB = outB;
        a.dh = dh; a.dc = dc; a.dg = dg; a.h2w = h2; a.c2w = c2; a.ow = o;
        a.logits = logits; a.sc = sc; a.part = part;
        a.tok = tok; a.prevK = prevK; a.nextY = nextY; a.cand = cand;
        a.outTok = (int*)d_out;
        a.bigws = bigws ? 1 : 0;
        a.npart = bigws ? 782 : GRID;
        void* params[] = { (void*)&a };
        err = hipLaunchCooperativeKernel((const void*)k_mega, dim3(GRID), dim3(256),
                                         params, 0, stream);
    }
    if (err != hipSuccess) {
        // fallback: validated R4 multi-launch path
        for (int t = 0; t <= SLEN; t++)
            k_enc<<<250, 256, 0, stream>>>(encWhh, X, gbuf, cbuf, ctx, dh, dc, sc, tok, t);
        const int npart = 782;
        for (int t = 0; t < MAXLEN; t++) {
            k_gates<<<125, 1024, 0, stream>>>(decEmb, decWih, decWhh, decBih, decBhh, tok, dh, dg);
            k_attn_oproj<<<125, 256, 0, stream>>>(dg, dc, ctx, attnW, h2, c2, o);
            if (bigws) k_logits4<<<782, 256, 0, stream>>>(outW4, outB, o, logits, part);
            else       k_logits_f<<<782, 256, 0, stream>>>(outW, outB, o, logits, part);
            k_topk_row<<<320, 256, 0, stream>>>(logits, cand);
            k_merge<<<1, 256, 0, stream>>>(part, npart, cand, sc, tok, h2, c2, dh, dc, prevK, nextY, t);
        }
        k_traceback<<<1, 64, 0, stream>>>(prevK, nextY, (int*)d_out);
    }
}

// Round 7
// 4216.423 us; speedup vs baseline: 1.0364x; 1.0002x over previous
//
#include <hip/hip_runtime.h>
#include <math.h>

#define BEAM   10
#define MAXLEN 32
#define SLEN   32
#define HD     500
#define ED     500
#define G4     2000
#define PV     50000
#define NEGF   (-1e30f)
#define NEGD   (-1.0e30)

#define GRID2  256          // mega grid: 1 block/CU guaranteed resident
#define NW     1024         // GRID2*4 waves
#define STRIP  196          // cols per block in logits phase (256*196 >= 50000)

typedef unsigned long long u64;

// ---------------- ws layout (float element offsets) ----------------
#define OFF_X      0
#define OFF_CBUF   64000
#define OFF_GBUF   65000
#define OFF_CTX    69000
#define OFF_DH     85000
#define OFF_DC     90000
#define OFF_DG     95000
#define OFF_H2     115000
#define OFF_C2     120000
#define OFF_O      125000
#define OFF_SCD    135000
#define OFF_TOK    135020
#define OFF_PREVK  135040
#define OFF_NEXTY  135360
// fallback-path regions (R4 layout)
#define OFF_PARTF  136000   // double[7820]
#define OFF_CANDF  152000   // u64[3200]
#define OFF_LOG    160000   // only used by fallback kernels
// mega-path regions (live inside the fallback LOG region; paths are exclusive)
#define OFF_BAR    160000   // int[8]: cnt, gen, done
#define OFF_LSE    160008   // double[10]
#define OFF_PARTD  160028   // double[10*256]
#define OFF_RC     165148   // u64[100]
#define OFF_CAND   165348   // u64[10*2560]
#define OFF_OWT    660000   // float4-blocked transposed out_W (100 MB)
#define NEED_T_BYTES ((size_t)(OFF_OWT + (size_t)HD * PV) * 4)

__device__ __forceinline__ float sigf(float x) { return 1.f / (1.f + expf(-x)); }

__device__ __forceinline__ unsigned fkey(float f) {
    unsigned u = __float_as_uint(f);
    return (u & 0x80000000u) ? ~u : (u | 0x80000000u);
}
__device__ __forceinline__ float unfkey(unsigned k) {
    unsigned u = (k & 0x80000000u) ? (k & 0x7fffffffu) : ~k;
    return __uint_as_float(u);
}

// hand-rolled grid barrier: all GRID2 blocks resident (1/CU) => spin is safe.
__device__ __forceinline__ void gbar(int* cnt, int* gen) {
    __syncthreads();
    if (threadIdx.x == 0) {
        int g = __hip_atomic_load(gen, __ATOMIC_RELAXED, __HIP_MEMORY_SCOPE_AGENT);
        int a = __hip_atomic_fetch_add(cnt, 1, __ATOMIC_ACQ_REL, __HIP_MEMORY_SCOPE_AGENT);
        if (a == GRID2 - 1) {
            __hip_atomic_store(cnt, 0, __ATOMIC_RELAXED, __HIP_MEMORY_SCOPE_AGENT);
            __hip_atomic_store(gen, g + 1, __ATOMIC_RELEASE, __HIP_MEMORY_SCOPE_AGENT);
        } else {
            while (__hip_atomic_load(gen, __ATOMIC_ACQUIRE, __HIP_MEMORY_SCOPE_AGENT) == g)
                __builtin_amdgcn_s_sleep(16);
        }
    }
    __syncthreads();
}

// ---------------- prep ----------------
__global__ void k_prep(const int* __restrict__ g_seq, const float* __restrict__ enc_emb,
                       const float* __restrict__ Wih, const float* __restrict__ bih,
                       const float* __restrict__ bhh, float* __restrict__ X,
                       float* __restrict__ cbuf0, int* __restrict__ bar) {
    if (blockIdx.x == 0) {
        for (int j = threadIdx.x; j < HD; j += 256) cbuf0[j] = 0.f;
        if (threadIdx.x < 8) bar[threadIdx.x] = 0;
    }
    int wv = (blockIdx.x * blockDim.x + threadIdx.x) >> 6;
    int lane = threadIdx.x & 63;
    if (wv >= SLEN * G4) return;
    int t = wv / G4, r = wv - t * G4;
    const float* emb = enc_emb + (size_t)g_seq[t] * ED;
    const float* w = Wih + (size_t)r * ED;
    float acc = 0.f;
    for (int ki = 0; ki < 8; ki++) { int k = ki * 64 + lane; if (k < ED) acc += emb[k] * w[k]; }
    for (int o = 32; o; o >>= 1) acc += __shfl_down(acc, o);
    if (lane == 0) X[t * G4 + r] = acc + bih[r] + bhh[r];
}

// ---------------- out_W blocked transpose ----------------
__global__ void k_transpose4(const float* __restrict__ outW, float* __restrict__ outW4) {
    __shared__ float t_lds[64][65];
    int tid = threadIdx.x;
    int pbase = blockIdx.x * 64, kbase = blockIdx.y * 64;
    for (int e = 0; e < 16; e++) {
        int idx = e * 256 + tid; int pl = idx >> 6, kl = idx & 63;
        int pp = pbase + pl, kk = kbase + kl;
        t_lds[pl][kl] = (pp < PV && kk < HD) ? outW[(size_t)pp * HD + kk] : 0.f;
    }
    __syncthreads();
    for (int e = 0; e < 4; e++) {
        int idx = e * 256 + tid;
        int pl = idx & 63, kb = idx >> 6;
        int pp = pbase + pl;
        int kglob = kbase + kb * 4;
        if (pp < PV && kglob < HD) {
            float4 v;
            v.x = t_lds[pl][kb * 4 + 0];
            v.y = t_lds[pl][kb * 4 + 1];
            v.z = t_lds[pl][kb * 4 + 2];
            v.w = t_lds[pl][kb * 4 + 3];
            *(float4*)(outW4 + ((size_t)(kbase / 4 + kb) * PV + pp) * 4) = v;
        }
    }
}

// ================= mega args =================
struct MegaA {
    const float* encWhh; const float* X;
    float* gbuf; float* cbuf; float* ctx;
    const float* decEmb; const float* decWih; const float* decWhh;
    const float* decBih; const float* decBhh; const float* attnW;
    const float* outW4; const float* outB;
    float* dh; float* dc; float* dg; float* h2w; float* c2w; float* ow;
    double* sc; double* part; double* lse;
    int* tok; int* prevK; int* nextY; u64* cand; u64* rc; int* outTok;
    int* bar;   // [0]=cnt [1]=gen [2]=done
};

struct MS {
    double scl[BEAM]; double lse2[BEAM];
    double bwv[4]; unsigned bwf[4]; unsigned winf;
    int pk[BEAM]; int ny[BEAM]; double val[BEAM];
};

// ================= persistent mega (normal launch, custom barrier) =================
__global__ __launch_bounds__(256) void k_mega2(MegaA A) {
    __shared__ __align__(16) char smem_raw[44032];
    float* smf = (float*)smem_raw;
    int* cnt = A.bar, * gen = A.bar + 1, * done = A.bar + 2;
    const int tid = threadIdx.x, bid = blockIdx.x;
    const int wv = tid >> 6, lane = tid & 63;
    const int gw = bid * 4 + wv;

    // ===== encoder: 33 steps =====
    for (int t = 0; t <= SLEN; ++t) {
        const float* gprev = A.gbuf + ((t + 1) & 1) * G4;
        float*       gcur  = A.gbuf + (t & 1) * G4;
        const float* cprev = A.cbuf + ((t + 1) & 1) * HD;
        float*       ccur  = A.cbuf + (t & 1) * HD;
        if (t < SLEN || bid == 0) {
            float* h_lds = smf;
            if (t > 0) {
                for (int j = tid; j < HD; j += 256) {
                    float gi = gprev[j], gf = gprev[HD + j], gg = gprev[2 * HD + j], go = gprev[3 * HD + j];
                    float c = sigf(gf) * cprev[j] + sigf(gi) * tanhf(gg);
                    float h = sigf(go) * tanhf(c);
                    h_lds[j] = h;
                    if (bid == 0) {
                        ccur[j] = c;
                        A.ctx[(t - 1) * HD + j] = h;
                        if (t == SLEN) {
                            for (int b = 0; b < BEAM; b++) { A.dh[b * HD + j] = h; A.dc[b * HD + j] = c; }
                        }
                    }
                }
            } else {
                for (int j = tid; j < HD; j += 256) h_lds[j] = 0.f;
            }
            if (t == SLEN && bid == 0 && tid == 0) {
                for (int b = 0; b < BEAM; b++) A.sc[b] = 0.0;
                A.tok[0] = 2; for (int b = 1; b < BEAM; b++) A.tok[b] = 1;
            }
            __syncthreads();
            if (t < SLEN) {
                for (int r = gw; r < G4; r += NW) {
                    const float* w = A.encWhh + (size_t)r * HD;
                    float acc = 0.f;
                    for (int ki = 0; ki < 8; ki++) { int k = ki * 64 + lane; if (k < HD) acc += h_lds[k] * w[k]; }
                    for (int o = 32; o; o >>= 1) acc += __shfl_down(acc, o);
                    if (lane == 0) gcur[r] = A.X[t * G4 + r] + acc;
                }
            }
        }
        gbar(cnt, gen);
    }

    // ===== decode: 32 steps x 4 barriers =====
    for (int t = 0; t < MAXLEN; ++t) {
        // ---- phase G: gates (all 256 blocks, rows strided) ----
        {
            float* e_lds = smf;               // 5000
            float* h_lds = smf + 5000;        // 5000
            for (int idx = tid; idx < BEAM * ED; idx += 256) {
                int b = idx / ED, k = idx - b * ED;
                e_lds[idx] = A.decEmb[(size_t)A.tok[b] * ED + k];
                h_lds[idx] = A.dh[idx];
            }
            __syncthreads();
            for (int r = gw; r < G4; r += NW) {
                const float* wi = A.decWih + (size_t)r * ED;
                const float* wh = A.decWhh + (size_t)r * HD;
                float acc[BEAM];
#pragma unroll
                for (int b = 0; b < BEAM; b++) acc[b] = 0.f;
                for (int ki = 0; ki < 8; ki++) {
                    int k = ki * 64 + lane;
                    if (k < ED) {
                        float w = wi[k];
#pragma unroll
                        for (int b = 0; b < BEAM; b++) acc[b] += w * e_lds[b * ED + k];
                    }
                }
                for (int ki = 0; ki < 8; ki++) {
                    int k = ki * 64 + lane;
                    if (k < HD) {
                        float w = wh[k];
#pragma unroll
                        for (int b = 0; b < BEAM; b++) acc[b] += w * h_lds[b * HD + k];
                    }
                }
#pragma unroll
                for (int b = 0; b < BEAM; b++) {
                    float v = acc[b];
                    for (int o = 32; o; o >>= 1) v += __shfl_down(v, o);
                    acc[b] = v;
                }
                if (lane == 0) {
                    float bb = A.decBih[r] + A.decBhh[r];
#pragma unroll
                    for (int b = 0; b < BEAM; b++) A.dg[b * G4 + r] = acc[b] + bb;
                }
            }
        }
        gbar(cnt, gen);

        // ---- phase A: LSTM pointwise + attention + oproj (blocks 0..124) ----
        if (bid < 125) {
            float* h2_lds   = smf;
            float* wctx_lds = smf + 5000;
            float* s_lds    = smf + 10000;
            float* a_lds    = smf + 10320;
            for (int idx = tid; idx < BEAM * HD; idx += 256) {
                int b = idx / HD, j = idx - b * HD;
                float gi = A.dg[b * G4 + j], gf = A.dg[b * G4 + HD + j];
                float gg = A.dg[b * G4 + 2 * HD + j], go = A.dg[b * G4 + 3 * HD + j];
                float c = sigf(gf) * A.dc[idx] + sigf(gi) * tanhf(gg);
                float h2 = sigf(go) * tanhf(c);
                h2_lds[idx] = h2;
                if (bid == 0) { A.c2w[idx] = c; A.h2w[idx] = h2; }
            }
            __syncthreads();
            for (int si = 0; si < 8; ++si) {
                int s = wv + 4 * si;
                float acc[BEAM];
#pragma unroll
                for (int b = 0; b < BEAM; b++) acc[b] = 0.f;
                for (int ki = 0; ki < 8; ki++) {
                    int k = ki * 64 + lane;
                    if (k < HD) {
                        float c = A.ctx[s * HD + k];
#pragma unroll
                        for (int b = 0; b < BEAM; b++) acc[b] += c * h2_lds[b * HD + k];
                    }
                }
#pragma unroll
                for (int b = 0; b < BEAM; b++) {
                    float v = acc[b];
                    for (int o = 32; o; o >>= 1) v += __shfl_down(v, o);
                    if (lane == 0) s_lds[b * SLEN + s] = v;
                }
            }
            __syncthreads();
            if (wv == 0) {
                for (int b = 0; b < BEAM; ++b) {
                    float v = (lane < SLEN) ? s_lds[b * SLEN + lane] : -INFINITY;
                    float m = v;
                    for (int o = 32; o; o >>= 1) m = fmaxf(m, __shfl_xor(m, o));
                    float e = (lane < SLEN) ? expf(v - m) : 0.f;
                    float sum = e;
                    for (int o = 32; o; o >>= 1) sum += __shfl_xor(sum, o);
                    if (lane < SLEN) a_lds[b * SLEN + lane] = e / sum;
                }
            }
            __syncthreads();
            {
                float w0[BEAM], w1[BEAM];
#pragma unroll
                for (int b = 0; b < BEAM; b++) { w0[b] = 0.f; w1[b] = 0.f; }
                int j0 = tid, j1 = tid + 256;
                for (int s = 0; s < SLEN; ++s) {
                    float c0 = (j0 < HD) ? A.ctx[s * HD + j0] : 0.f;
                    float c1 = (j1 < HD) ? A.ctx[s * HD + j1] : 0.f;
#pragma unroll
                    for (int b = 0; b < BEAM; b++) {
                        float a = a_lds[b * SLEN + s];
                        w0[b] += a * c0; w1[b] += a * c1;
                    }
                }
#pragma unroll
                for (int b = 0; b < BEAM; b++) {
                    if (j0 < HD) wctx_lds[b * HD + j0] = w0[b];
                    if (j1 < HD) wctx_lds[b * HD + j1] = w1[b];
                }
            }
            __syncthreads();
            int j = gw;
            const float* w = A.attnW + (size_t)j * 1000;
            float acc[BEAM];
#pragma unroll
            for (int b = 0; b < BEAM; b++) acc[b] = 0.f;
            for (int ki = 0; ki < 16; ki++) {
                int k = ki * 64 + lane;
                if (k < 1000) {
                    float wk = w[k];
#pragma unroll
                    for (int b = 0; b < BEAM; b++) {
                        float h = (k < HD) ? h2_lds[b * HD + k] : wctx_lds[b * HD + k - HD];
                        acc[b] += wk * h;
                    }
                }
            }
#pragma unroll
            for (int b = 0; b < BEAM; b++) {
                float v = acc[b];
                for (int o = 32; o; o >>= 1) v += __shfl_down(v, o);
                acc[b] = v;
            }
            if (lane == 0) {
#pragma unroll
                for (int b = 0; b < BEAM; b++) A.ow[b * HD + j] = tanhf(acc[b]);
            }
        }
        gbar(cnt, gen);

        // ---- phase L+T: logits (1 col/thread) + per-strip top-10 + fp64 partial sumexp ----
        {
            float4* o4 = (float4*)smem_raw;   // 1250 float4 = 20000 B
            for (int idx = tid; idx < BEAM * 125; idx += 256) {
                int b = idx / 125, kb = idx - b * 125;
                o4[idx] = *(const float4*)(A.ow + b * HD + kb * 4);
            }
            __syncthreads();
            int p = bid * STRIP + tid;
            bool valid = (tid < STRIP) && (p < PV);
            int pc = (p < PV) ? p : (PV - 1);
            float lg[BEAM];
            {
                float acc[BEAM];
#pragma unroll
                for (int b = 0; b < BEAM; b++) acc[b] = 0.f;
                const float4* wp = (const float4*)A.outW4;
                for (int kb = 0; kb < 125; ++kb) {
                    float4 w = wp[(size_t)kb * PV + pc];
#pragma unroll
                    for (int b = 0; b < BEAM; b++) {
                        float4 o = o4[b * 125 + kb];
                        acc[b] += w.x * o.x + w.y * o.y + w.z * o.z + w.w * o.w;
                    }
                }
                float ob = A.outB[pc];
#pragma unroll
                for (int b = 0; b < BEAM; b++) lg[b] = acc[b] + ob;
            }
            // fp64 partial sumexp per row
            double* pd = (double*)(smem_raw + 20480);
#pragma unroll
            for (int b = 0; b < BEAM; b++) pd[b * 256 + tid] = valid ? exp((double)lg[b]) : 0.0;
            __syncthreads();
            for (int r = wv; r < BEAM; r += 4) {
                double s = pd[r * 256 + lane] + pd[r * 256 + 64 + lane]
                         + pd[r * 256 + 128 + lane] + pd[r * 256 + 192 + lane];
                for (int o = 32; o; o >>= 1) s += __shfl_down(s, o);
                if (lane == 0) A.part[r * 256 + bid] = s;
            }
            __syncthreads();
            // per-strip per-row top-10
            u64* kl = (u64*)(smem_raw + 20480);
#pragma unroll
            for (int b = 0; b < BEAM; b++)
                kl[b * 256 + tid] = valid ? (((u64)fkey(lg[b]) << 32) | (unsigned)(~(unsigned)p)) : 0ull;
            __syncthreads();
            for (int r = wv; r < BEAM; r += 4) {
                u64 kk[4];
#pragma unroll
                for (int j = 0; j < 4; j++) kk[j] = kl[r * 256 + j * 64 + lane];
                for (int round = 0; round < BEAM; round++) {
                    u64 m = kk[0];
                    if (kk[1] > m) m = kk[1];
                    if (kk[2] > m) m = kk[2];
                    if (kk[3] > m) m = kk[3];
                    for (int o = 32; o; o >>= 1) {
                        u64 t2 = __shfl_down(m, o);
                        if (t2 > m) m = t2;
                    }
                    u64 win = __shfl(m, 0);
#pragma unroll
                    for (int j = 0; j < 4; j++) if (kk[j] == win) kk[j] = 0ull;
                    if (lane == 0) A.cand[(size_t)r * 2560 + bid * 10 + round] = win;
                }
            }
        }
        gbar(cnt, gen);

        // ---- phase RM+M: per-row merge (blocks 0..9) + last-block global merge ----
        if (bid < BEAM) {
            int r = bid;
            double* redd = (double*)(smem_raw + 40960);
            u64* wred = (u64*)(smem_raw + 41024);
            u64* winp = (u64*)(smem_raw + 41056);
            int* lastf = (int*)(smem_raw + 41072);
            // lse
            {
                double s = A.part[r * 256 + tid];
                for (int o = 32; o; o >>= 1) s += __shfl_down(s, o);
                if (lane == 0) redd[wv] = s;
                __syncthreads();
                if (tid == 0) A.lse[r] = log(redd[0] + redd[1] + redd[2] + redd[3]);
            }
            // row top-10 over 2560 strip candidates
            u64 kk[10];
#pragma unroll
            for (int e = 0; e < 10; e++) kk[e] = A.cand[(size_t)r * 2560 + e * 256 + tid];
            for (int round = 0; round < BEAM; round++) {
                u64 m = 0ull;
#pragma unroll
                for (int e = 0; e < 10; e++) if (kk[e] > m) m = kk[e];
                for (int o = 32; o; o >>= 1) {
                    u64 t2 = __shfl_down(m, o);
                    if (t2 > m) m = t2;
                }
                if (lane == 0) wred[wv] = m;
                __syncthreads();
                if (tid == 0) {
                    u64 wn = wred[0];
                    for (int i = 1; i < 4; i++) if (wred[i] > wn) wn = wred[i];
                    *winp = wn;
                    A.rc[r * 10 + round] = wn;
                }
                __syncthreads();
                u64 win = *winp;
#pragma unroll
                for (int e = 0; e < 10; e++) if (kk[e] == win) kk[e] = 0ull;
                __syncthreads();
            }
            // last row-block performs the global merge
            if (tid == 0) {
                int old = __hip_atomic_fetch_add(done, 1, __ATOMIC_ACQ_REL, __HIP_MEMORY_SCOPE_AGENT);
                *lastf = (old == BEAM - 1) ? 1 : 0;
            }
            __syncthreads();
            if (*lastf) {
                MS* M = (MS*)(smem_raw + 41216);
                if (tid < BEAM) { M->scl[tid] = A.sc[tid]; M->lse2[tid] = A.lse[tid]; }
                __syncthreads();
                double cv = -1.0e308; unsigned cf = 0xFFFFFFFFu;
                if (tid < BEAM * BEAM) {
                    u64 k0 = A.rc[tid];
                    if (k0) {
                        int r2 = tid / BEAM;
                        float v = unfkey((unsigned)(k0 >> 32));
                        unsigned p = ~((unsigned)k0);
                        double v2;
                        if (t == 0) v2 = (r2 == 0) ? ((double)v - M->lse2[0]) : NEGD;
                        else        v2 = ((double)v - M->lse2[r2]) + M->scl[r2];
                        cv = v2;
                        cf = (unsigned)r2 * PV + p;
                    }
                }
                for (int round = 0; round < BEAM; round++) {
                    double bv = cv; unsigned bf = cf;
                    for (int o = 32; o; o >>= 1) {
                        double ov = __shfl_down(bv, o);
                        unsigned of = __shfl_down(bf, o);
                        if (ov > bv || (ov == bv && of < bf)) { bv = ov; bf = of; }
                    }
                    if (lane == 0) { M->bwv[wv] = bv; M->bwf[wv] = bf; }
                    __syncthreads();
                    if (tid == 0) {
                        double xv = M->bwv[0]; unsigned xf = M->bwf[0];
                        for (int i = 1; i < 4; i++) {
                            if (M->bwv[i] > xv || (M->bwv[i] == xv && M->bwf[i] < xf)) { xv = M->bwv[i]; xf = M->bwf[i]; }
                        }
                        M->winf = xf;
                        int pk = (int)(xf / PV);
                        int ny = (int)(xf - (unsigned)pk * PV);
                        M->pk[round] = pk; M->ny[round] = ny; M->val[round] = xv;
                    }
                    __syncthreads();
                    if (cf == M->winf) { cv = -1.0e308; cf = 0xFFFFFFFFu; }
                    __syncthreads();
                }
                if (tid < BEAM) {
                    A.sc[tid] = M->val[tid];
                    A.tok[tid] = M->ny[tid];
                    A.prevK[t * BEAM + tid] = M->pk[tid];
                    A.nextY[t * BEAM + tid] = M->ny[tid];
                }
                __syncthreads();
                for (int idx = tid; idx < BEAM * HD; idx += 256) {
                    int i = idx / HD, j = idx - i * HD;
                    A.dh[idx] = A.h2w[M->pk[i] * HD + j];
                    A.dc[idx] = A.c2w[M->pk[i] * HD + j];
                }
                if (tid == 0) __hip_atomic_store(done, 0, __ATOMIC_RELAXED, __HIP_MEMORY_SCOPE_AGENT);
            }
        }
        gbar(cnt, gen);
    }

    // ===== traceback =====
    if (bid == 0 && tid < BEAM) {
        int cur = tid;
        for (int tt = MAXLEN - 1; tt >= 0; tt--) {
            A.outTok[tid * MAXLEN + tt] = A.nextY[tt * BEAM + cur];
            cur = A.prevK[tt * BEAM + cur];
        }
    }
}

// ======================================================================
// R4 fallback kernels (validated multi-launch path)
// ======================================================================
__global__ void k_enc(const float* __restrict__ Whh, const float* __restrict__ X,
                      float* __restrict__ gbuf, float* __restrict__ cbuf,
                      float* __restrict__ context, float* __restrict__ dec_h,
                      float* __restrict__ dec_c, double* __restrict__ scores,
                      int* __restrict__ tokens, int t) {
    __shared__ float h_lds[HD];
    const float* gprev = gbuf + ((t + 1) & 1) * G4;
    float*       gcur  = gbuf + (t & 1) * G4;
    const float* cprev = cbuf + ((t + 1) & 1) * HD;
    float*       ccur  = cbuf + (t & 1) * HD;
    int tid = threadIdx.x;
    if (t > 0) {
        for (int j = tid; j < HD; j += 256) {
            float gi = gprev[j], gf = gprev[HD + j], gg = gprev[2 * HD + j], go = gprev[3 * HD + j];
            float c = sigf(gf) * cprev[j] + sigf(gi) * tanhf(gg);
            float h = sigf(go) * tanhf(c);
            h_lds[j] = h;
            if (blockIdx.x == 0) {
                ccur[j] = c;
                context[(t - 1) * HD + j] = h;
                if (t == SLEN) {
                    for (int b = 0; b < BEAM; b++) { dec_h[b * HD + j] = h; dec_c[b * HD + j] = c; }
                }
            }
        }
    } else {
        for (int j = tid; j < HD; j += 256) h_lds[j] = 0.f;
    }
    if (t == SLEN && blockIdx.x == 0 && tid == 0) {
        for (int b = 0; b < BEAM; b++) scores[b] = 0.0;
        tokens[0] = 2; for (int b = 1; b < BEAM; b++) tokens[b] = 1;
    }
    __syncthreads();
    if (t < SLEN) {
        int wv = blockIdx.x * 4 + (tid >> 6), lane = tid & 63;
        for (int r = wv; r < G4; r += 1000) {
            const float* w = Whh + (size_t)r * HD;
            float acc = 0.f;
            for (int ki = 0; ki < 8; ki++) { int k = ki * 64 + lane; if (k < HD) acc += h_lds[k] * w[k]; }
            for (int o = 32; o; o >>= 1) acc += __shfl_down(acc, o);
            if (lane == 0) gcur[r] = X[t * G4 + r] + acc;
        }
    }
}

__global__ __launch_bounds__(1024) void k_gates(
        const float* __restrict__ dec_emb, const float* __restrict__ Wih,
        const float* __restrict__ Whh, const float* __restrict__ bih,
        const float* __restrict__ bhh, const int* __restrict__ tokens,
        const float* __restrict__ h_ws, float* __restrict__ gates) {
    __shared__ float e_lds[BEAM * ED];
    __shared__ float h_lds[BEAM * HD];
    int tid = threadIdx.x;
    for (int idx = tid; idx < BEAM * ED; idx += 1024) {
        int b = idx / ED, k = idx - b * ED;
        e_lds[idx] = dec_emb[(size_t)tokens[b] * ED + k];
        h_lds[idx] = h_ws[idx];
    }
    __syncthreads();
    int wv = tid >> 6, lane = tid & 63;
    int r = blockIdx.x * 16 + wv;
    const float* wi = Wih + (size_t)r * ED;
    const float* wh = Whh + (size_t)r * HD;
    float acc[BEAM];
#pragma unroll
    for (int b = 0; b < BEAM; b++) acc[b] = 0.f;
    for (int ki = 0; ki < 8; ki++) {
        int k = ki * 64 + lane;
        if (k < ED) {
            float w = wi[k];
#pragma unroll
            for (int b = 0; b < BEAM; b++) acc[b] += w * e_lds[b * ED + k];
        }
    }
    for (int ki = 0; ki < 8; ki++) {
        int k = ki * 64 + lane;
        if (k < HD) {
            float w = wh[k];
#pragma unroll
            for (int b = 0; b < BEAM; b++) acc[b] += w * h_lds[b * HD + k];
        }
    }
#pragma unroll
    for (int b = 0; b < BEAM; b++) {
        float v = acc[b];
        for (int o = 32; o; o >>= 1) v += __shfl_down(v, o);
        acc[b] = v;
    }
    if (lane == 0) {
        float bb = bih[r] + bhh[r];
#pragma unroll
        for (int b = 0; b < BEAM; b++) gates[b * G4 + r] = acc[b] + bb;
    }
}

__global__ __launch_bounds__(256) void k_attn_oproj(
        const float* __restrict__ gates, const float* __restrict__ c_ws,
        const float* __restrict__ context, const float* __restrict__ attnW,
        float* __restrict__ h2_ws, float* __restrict__ c2_ws, float* __restrict__ o_ws) {
    __shared__ float h2_lds[BEAM * HD];
    __shared__ float wctx_lds[BEAM * HD];
    __shared__ float s_lds[BEAM * SLEN];
    __shared__ float a_lds[BEAM * SLEN];
    int tid = threadIdx.x;
    int wv = tid >> 6, lane = tid & 63;
    for (int idx = tid; idx < BEAM * HD; idx += 256) {
        int b = idx / HD, j = idx - b * HD;
        float gi = gates[b * G4 + j], gf = gates[b * G4 + HD + j];
        float gg = gates[b * G4 + 2 * HD + j], go = gates[b * G4 + 3 * HD + j];
        float c = sigf(gf) * c_ws[idx] + sigf(gi) * tanhf(gg);
        float h2 = sigf(go) * tanhf(c);
        h2_lds[idx] = h2;
        if (blockIdx.x == 0) { c2_ws[idx] = c; h2_ws[idx] = h2; }
    }
    __syncthreads();
    for (int si = 0; si < 8; ++si) {
        int s = wv + 4 * si;
        float acc[BEAM];
#pragma unroll
        for (int b = 0; b < BEAM; b++) acc[b] = 0.f;
        for (int ki = 0; ki < 8; ki++) {
            int k = ki * 64 + lane;
            if (k < HD) {
                float c = context[s * HD + k];
#pragma unroll
                for (int b = 0; b < BEAM; b++) acc[b] += c * h2_lds[b * HD + k];
            }
        }
#pragma unroll
        for (int b = 0; b < BEAM; b++) {
            float v = acc[b];
            for (int o = 32; o; o >>= 1) v += __shfl_down(v, o);
            if (lane == 0) s_lds[b * SLEN + s] = v;
        }
    }
    __syncthreads();
    if (wv == 0) {
        for (int b = 0; b < BEAM; ++b) {
            float v = (lane < SLEN) ? s_lds[b * SLEN + lane] : -INFINITY;
            float m = v;
            for (int o = 32; o; o >>= 1) m = fmaxf(m, __shfl_xor(m, o));
            float e = (lane < SLEN) ? expf(v - m) : 0.f;
            float sum = e;
            for (int o = 32; o; o >>= 1) sum += __shfl_xor(sum, o);
            if (lane < SLEN) a_lds[b * SLEN + lane] = e / sum;
        }
    }
    __syncthreads();
    {
        float w0[BEAM], w1[BEAM];
#pragma unroll
        for (int b = 0; b < BEAM; b++) { w0[b] = 0.f; w1[b] = 0.f; }
        int j0 = tid, j1 = tid + 256;
        for (int s = 0; s < SLEN; ++s) {
            float c0 = (j0 < HD) ? context[s * HD + j0] : 0.f;
            float c1 = (j1 < HD) ? context[s * HD + j1] : 0.f;
#pragma unroll
            for (int b = 0; b < BEAM; b++) {
                float a = a_lds[b * SLEN + s];
                w0[b] += a * c0; w1[b] += a * c1;
            }
        }
#pragma unroll
        for (int b = 0; b < BEAM; b++) {
            if (j0 < HD) wctx_lds[b * HD + j0] = w0[b];
            if (j1 < HD) wctx_lds[b * HD + j1] = w1[b];
        }
    }
    __syncthreads();
    int j = blockIdx.x * 4 + wv;
    const float* w = attnW + (size_t)j * 1000;
    float acc[BEAM];
#pragma unroll
    for (int b = 0; b < BEAM; b++) acc[b] = 0.f;
    for (int ki = 0; ki < 16; ki++) {
        int k = ki * 64 + lane;
        if (k < 1000) {
            float wk = w[k];
#pragma unroll
            for (int b = 0; b < BEAM; b++) {
                float h = (k < HD) ? h2_lds[b * HD + k] : wctx_lds[b * HD + k - HD];
                acc[b] += wk * h;
            }
        }
    }
#pragma unroll
    for (int b = 0; b < BEAM; b++) {
        float v = acc[b];
        for (int o = 32; o; o >>= 1) v += __shfl_down(v, o);
        acc[b] = v;
    }
    if (lane == 0) {
#pragma unroll
        for (int b = 0; b < BEAM; b++) o_ws[b * HD + j] = tanhf(acc[b]);
    }
}

__global__ __launch_bounds__(256) void k_logits4(
        const float* __restrict__ outW4, const float* __restrict__ outB,
        const float* __restrict__ o_ws, float* __restrict__ logits,
        double* __restrict__ partials) {
    __shared__ __align__(16) float4 o4[BEAM * 125];
    __shared__ float part[4][64][BEAM];
    int tid = threadIdx.x;
    for (int idx = tid; idx < BEAM * 125; idx += 256) {
        int b = idx / 125, kb = idx - b * 125;
        o4[idx] = *(const float4*)(o_ws + b * HD + kb * 4);
    }
    __syncthreads();
    int kc = tid >> 6, pl = tid & 63;
    int p = blockIdx.x * 64 + pl;
    int pc = (p < PV) ? p : (PV - 1);
    int kb0 = kc * 32, kb1 = (kc == 3) ? 125 : (kb0 + 32);
    float acc[BEAM];
#pragma unroll
    for (int b = 0; b < BEAM; b++) acc[b] = 0.f;
    const float4* wp = (const float4*)outW4;
    for (int kb = kb0; kb < kb1; ++kb) {
        float4 w = wp[(size_t)kb * PV + pc];
#pragma unroll
        for (int b = 0; b < BEAM; b++) {
            float4 o = o4[b * 125 + kb];
            acc[b] += w.x * o.x + w.y * o.y + w.z * o.z + w.w * o.w;
        }
    }
#pragma unroll
    for (int b = 0; b < BEAM; b++) part[kc][pl][b] = acc[b];
    __syncthreads();
    if (tid < 64) {
        int p2 = blockIdx.x * 64 + tid;
        bool valid = (p2 < PV);
        float ob = outB[valid ? p2 : 0];
        double es[BEAM];
#pragma unroll
        for (int b = 0; b < BEAM; b++) {
            float lg = part[0][tid][b] + part[1][tid][b] + part[2][tid][b] + part[3][tid][b] + ob;
            if (valid) logits[(size_t)b * PV + p2] = lg;
            es[b] = valid ? exp((double)lg) : 0.0;
        }
#pragma unroll
        for (int b = 0; b < BEAM; b++) {
            for (int o = 32; o; o >>= 1) es[b] += __shfl_down(es[b], o);
        }
        if (tid == 0) {
#pragma unroll
            for (int b = 0; b < BEAM; b++) partials[blockIdx.x * BEAM + b] = es[b];
        }
    }
}

__global__ void k_logits_f(const float* __restrict__ outW, const float* __restrict__ outB,
                           const float* __restrict__ o_ws, float* __restrict__ logits,
                           double* __restrict__ partials) {
    __shared__ float o_lds[BEAM * HD];
    __shared__ double ered[4][BEAM];
    int tid = threadIdx.x;
    for (int idx = tid; idx < BEAM * HD; idx += 256) o_lds[idx] = o_ws[idx];
    __syncthreads();
    int wv = tid >> 6, lane = tid & 63;
    int w = blockIdx.x * 4 + wv;
    double esum = 0.0;
    for (int pi = 0; pi < 16; pi++) {
        int p = w * 16 + pi;
        if (p >= PV) break;
        const float* wr = outW + (size_t)p * HD;
        float acc[BEAM];
#pragma unroll
        for (int b = 0; b < BEAM; b++) acc[b] = 0.f;
        for (int ki = 0; ki < 8; ki++) {
            int k = ki * 64 + lane;
            if (k < HD) {
                float x = wr[k];
#pragma unroll
                for (int b = 0; b < BEAM; b++) acc[b] += x * o_lds[b * HD + k];
            }
        }
#pragma unroll
        for (int b = 0; b < BEAM; b++)
            for (int o = 32; o; o >>= 1) acc[b] += __shfl_xor(acc[b], o);
        if (lane < BEAM) {
            float lg = 0.f;
#pragma unroll
            for (int b = 0; b < BEAM; b++) if (lane == b) lg = acc[b];
            lg += outB[p];
            logits[(size_t)lane * PV + p] = lg;
            esum += exp((double)lg);
        }
    }
    if (lane < BEAM) ered[wv][lane] = esum;
    __syncthreads();
    if (tid < BEAM) partials[blockIdx.x * BEAM + tid] =
        ered[0][tid] + ered[1][tid] + ered[2][tid] + ered[3][tid];
}

__global__ __launch_bounds__(256) void k_topk_row(const float* __restrict__ logits,
                                                  u64* __restrict__ cands) {
    const int CH = 1563;
    int r = blockIdx.x >> 5, ci = blockIdx.x & 31;
    int base = ci * CH;
    int tid = threadIdx.x;
    int wv = tid >> 6, lane = tid & 63;
    u64 key[7];
#pragma unroll
    for (int e = 0; e < 7; e++) {
        int p = base + e * 256 + tid;
        key[e] = 0ull;
        if (p < base + CH && p < PV) {
            float v = logits[(size_t)r * PV + p];
            key[e] = ((u64)fkey(v) << 32) | (unsigned)(~(unsigned)p);
        }
    }
    __shared__ u64 wred[4];
    __shared__ u64 winlds;
    for (int round = 0; round < BEAM; round++) {
        u64 mx = 0ull;
#pragma unroll
        for (int e = 0; e < 7; e++) if (key[e] > mx) mx = key[e];
        for (int o = 32; o; o >>= 1) {
            u64 other = __shfl_down(mx, o);
            if (other > mx) mx = other;
        }
        if (lane == 0) wred[wv] = mx;
        __syncthreads();
        if (tid == 0) {
            u64 wn = wred[0];
            for (int i = 1; i < 4; i++) if (wred[i] > wn) wn = wred[i];
            winlds = wn;
            cands[blockIdx.x * BEAM + round] = wn;
        }
        __syncthreads();
        u64 win = winlds;
#pragma unroll
        for (int e = 0; e < 7; e++) if (key[e] == win) key[e] = 0ull;
    }
}

__global__ __launch_bounds__(256) void k_merge(
        const double* __restrict__ partials, int npart,
        const u64* __restrict__ cands,
        double* __restrict__ scores, int* __restrict__ tokens,
        const float* __restrict__ h2_ws, const float* __restrict__ c2_ws,
        float* __restrict__ h_ws, float* __restrict__ c_ws,
        int* __restrict__ prevKs, int* __restrict__ nextYs, int t) {
    __shared__ double wredd[4];
    __shared__ double lse_lds[BEAM];
    __shared__ double sc_lds[BEAM];
    __shared__ double bwv[4];
    __shared__ unsigned bwf[4];
    __shared__ unsigned winf_s;
    __shared__ int pk_lds[BEAM];
    __shared__ int ny_lds[BEAM];
    __shared__ double val_lds[BEAM];
    int tid = threadIdx.x;
    int wv = tid >> 6, lane = tid & 63;
    if (tid < BEAM) sc_lds[tid] = scores[tid];
    for (int b = 0; b < BEAM; b++) {
        double s = 0.0;
        for (int j = tid; j < npart; j += 256) s += partials[j * BEAM + b];
        for (int o = 32; o; o >>= 1) s += __shfl_down(s, o);
        if (lane == 0) wredd[wv] = s;
        __syncthreads();
        if (tid == 0) lse_lds[b] = log(wredd[0] + wredd[1] + wredd[2] + wredd[3]);
        __syncthreads();
    }
    double   cv[13];
    unsigned cf[13];
#pragma unroll
    for (int e = 0; e < 13; e++) {
        int c = e * 256 + tid;
        cv[e] = -1.0e308; cf[e] = 0xFFFFFFFFu;
        if (c < 3200) {
            u64 k0 = cands[c];
            if (k0) {
                int r = c / 320;
                float v = unfkey((unsigned)(k0 >> 32));
                unsigned p = ~((unsigned)k0);
                double v2;
                if (t == 0) v2 = (r == 0) ? ((double)v - lse_lds[0]) : (double)NEGF;
                else        v2 = ((double)v - lse_lds[r]) + sc_lds[r];
                cv[e] = v2;
                cf[e] = (unsigned)r * PV + p;
            }
        }
    }
    for (int round = 0; round < BEAM; round++) {
        double bv = -1.0e308; unsigned bf = 0xFFFFFFFFu;
#pragma unroll
        for (int e = 0; e < 13; e++) {
            if (cv[e] > bv || (cv[e] == bv && cf[e] < bf)) { bv = cv[e]; bf = cf[e]; }
        }
        for (int o = 32; o; o >>= 1) {
            double ov = __shfl_down(bv, o);
            unsigned of = __shfl_down(bf, o);
            if (ov > bv || (ov == bv && of < bf)) { bv = ov; bf = of; }
        }
        if (lane == 0) { bwv[wv] = bv; bwf[wv] = bf; }
        __syncthreads();
        if (tid == 0) {
            double xv = bwv[0]; unsigned xf = bwf[0];
            for (int i = 1; i < 4; i++) {
                if (bwv[i] > xv || (bwv[i] == xv && bwf[i] < xf)) { xv = bwv[i]; xf = bwf[i]; }
            }
            winf_s = xf;
            int pk = (int)(xf / PV);
            int ny = (int)(xf - (unsigned)pk * PV);
            pk_lds[round] = pk; ny_lds[round] = ny; val_lds[round] = xv;
        }
        __syncthreads();
        unsigned wff = winf_s;
#pragma unroll
        for (int e = 0; e < 13; e++) {
            if (cf[e] == wff) { cv[e] = -1.0e308; cf[e] = 0xFFFFFFFFu; }
        }
    }
    if (tid < BEAM) {
        scores[tid] = val_lds[tid];
        tokens[tid] = ny_lds[tid];
        prevKs[t * BEAM + tid] = pk_lds[tid];
        nextYs[t * BEAM + tid] = ny_lds[tid];
    }
    __syncthreads();
    for (int idx = tid; idx < BEAM * HD; idx += 256) {
        int i = idx / HD, j = idx - i * HD;
        h_ws[idx] = h2_ws[pk_lds[i] * HD + j];
        c_ws[idx] = c2_ws[pk_lds[i] * HD + j];
    }
}

__global__ void k_traceback(const int* __restrict__ prevKs, const int* __restrict__ nextYs,
                            int* __restrict__ out) {
    int k = threadIdx.x;
    if (k >= BEAM) return;
    int cur = k;
    for (int t = MAXLEN - 1; t >= 0; t--) {
        out[k * MAXLEN + t] = nextYs[t * BEAM + cur];
        cur = prevKs[t * BEAM + cur];
    }
}

extern "C" void kernel_launch(void* const* d_in, const int* in_sizes, int n_in,
                              void* d_out, int out_size, void* d_ws, size_t ws_size,
                              hipStream_t stream) {
    const int*   g_seq  = (const int*)  d_in[0];
    const float* encEmb = (const float*)d_in[1];
    const float* encWih = (const float*)d_in[2];
    const float* encWhh = (const float*)d_in[3];
    const float* encBih = (const float*)d_in[4];
    const float* encBhh = (const float*)d_in[5];
    const float* decEmb = (const float*)d_in[6];
    const float* decWih = (const float*)d_in[7];
    const float* decWhh = (const float*)d_in[8];
    const float* decBih = (const float*)d_in[9];
    const float* decBhh = (const float*)d_in[10];
    const float* attnW  = (const float*)d_in[11];
    const float* outW   = (const float*)d_in[12];
    const float* outB   = (const float*)d_in[13];

    float* ws = (float*)d_ws;
    float*  X     = ws + OFF_X;
    float*  cbuf  = ws + OFF_CBUF;
    float*  gbuf  = ws + OFF_GBUF;
    float*  ctx   = ws + OFF_CTX;
    float*  dh    = ws + OFF_DH;
    float*  dc    = ws + OFF_DC;
    float*  dg    = ws + OFF_DG;
    float*  h2    = ws + OFF_H2;
    float*  c2    = ws + OFF_C2;
    float*  o     = ws + OFF_O;
    double* sc    = (double*)(ws + OFF_SCD);
    int*    tok   = (int*)(ws + OFF_TOK);
    int*    prevK = (int*)(ws + OFF_PREVK);
    int*    nextY = (int*)(ws + OFF_NEXTY);
    int*    bar   = (int*)(ws + OFF_BAR);
    float*  outW4 = ws + OFF_OWT;

    bool bigws = (ws_size >= NEED_T_BYTES);

    k_prep<<<16000, 256, 0, stream>>>(g_seq, encEmb, encWih, encBih, encBhh, X, cbuf, bar);
    if (bigws) k_transpose4<<<dim3(782, 8), 256, 0, stream>>>(outW, outW4);

    // residency guard for the persistent mega: need >= GRID2 co-resident blocks
    bool mega_ok = bigws;
    if (mega_ok) {
        int dev = 0;
        hipDeviceProp_t prop;
        int occ = 0;
        if (hipGetDevice(&dev) != hipSuccess ||
            hipGetDeviceProperties(&prop, dev) != hipSuccess ||
            hipOccupancyMaxActiveBlocksPerMultiprocessor(&occ, (const void*)k_mega2, 256, 0) != hipSuccess ||
            (long long)occ * prop.multiProcessorCount < GRID2) {
            mega_ok = false;
        }
    }

    if (mega_ok) {
        MegaA a;
        a.encWhh = encWhh; a.X = X;
        a.gbuf = gbuf; a.cbuf = cbuf; a.ctx = ctx;
        a.decEmb = decEmb; a.decWih = decWih; a.decWhh = decWhh;
        a.decBih = decBih; a.decBhh = decBhh; a.attnW = attnW;
        a.outW4 = outW4; a.outB = outB;
        a.dh = dh; a.dc = dc; a.dg = dg; a.h2w = h2; a.c2w = c2; a.ow = o;
        a.sc = sc; a.part = (double*)(ws + OFF_PARTD); a.lse = (double*)(ws + OFF_LSE);
        a.tok = tok; a.prevK = prevK; a.nextY = nextY;
        a.cand = (u64*)(ws + OFF_CAND); a.rc = (u64*)(ws + OFF_RC);
        a.outTok = (int*)d_out; a.bar = bar;
        k_mega2<<<GRID2, 256, 0, stream>>>(a);
    } else {
        double* part  = (double*)(ws + OFF_PARTF);
        u64*    cand  = (u64*)(ws + OFF_CANDF);
        float*  logits = ws + OFF_LOG;
        for (int t = 0; t <= SLEN; t++)
            k_enc<<<250, 256, 0, stream>>>(encWhh, X, gbuf, cbuf, ctx, dh, dc, sc, tok, t);
        const int npart = 782;
        for (int t = 0; t < MAXLEN; t++) {
            k_gates<<<125, 1024, 0, stream>>>(decEmb, decWih, decWhh, decBih, decBhh, tok, dh, dg);
            k_attn_oproj<<<125, 256, 0, stream>>>(dg, dc, ctx, attnW, h2, c2, o);
            if (bigws) k_logits4<<<782, 256, 0, stream>>>(outW4, outB, o, logits, part);
            else       k_logits_f<<<782, 256, 0, stream>>>(outW, outB, o, logits, part);
            k_topk_row<<<320, 256, 0, stream>>>(logits, cand);
            k_merge<<<1, 256, 0, stream>>>(part, npart, cand, sc, tok, h2, c2, dh, dc, prevK, nextY, t);
        }
        k_traceback<<<1, 64, 0, stream>>>(prevK, nextY, (int*)d_out);
    }
}